// Round 12
// baseline (1907.766 us; speedup 1.0000x reference)
//
#include <hip/hip_runtime.h>
#include <hip/hip_bf16.h>
#include <cstdint>
#include <cstddef>

#define DEPTH 6
#define DIM   1024
#define HEADS 16
#define DIMH  64
#define INNER 1024
#define DFF   4096
#define SEQ   2048
#define NTOK  4096   // 2 * 2048

typedef __attribute__((ext_vector_type(8))) short bf16x8;
typedef __attribute__((ext_vector_type(4))) short bf16x4;
typedef __attribute__((ext_vector_type(4))) float f32x4;
typedef __hip_bfloat16 bf16;

#define CS 0.18033688011112042f  // SCALE * log2(e)
#define SMAX 24.0f               // static softmax max (exp2 domain)

__device__ __forceinline__ void gld_lds16(const void* g, void* l) {
  __builtin_amdgcn_global_load_lds(
      (const __attribute__((address_space(1))) unsigned int*)g,
      (__attribute__((address_space(3))) unsigned int*)l,
      16, 0, 0);
}

// ---------------------------------------------------------------------------
// Weight transpose + fp32->bf16 convert: in [D][K][N] -> out [D][orows][K]
// ---------------------------------------------------------------------------
__global__ __launch_bounds__(256) void transpose_convert(
    const float* __restrict__ in, bf16* __restrict__ out,
    int K, int N, int row0, int orows)
{
  __shared__ float tile[32][33];
  const int d  = blockIdx.z;
  const int n0 = blockIdx.x * 32, k0 = blockIdx.y * 32;
  const int c = threadIdx.x & 31, rb = threadIdx.x >> 5;
  const float* src = in + ((size_t)d * K + k0) * N + n0;
#pragma unroll
  for (int rr = 0; rr < 4; ++rr) {
    int r = rb + rr * 8;
    tile[r][c] = src[(size_t)r * N + c];
  }
  __syncthreads();
  bf16* dst = out + ((size_t)d * orows + row0 + n0) * K + k0;
#pragma unroll
  for (int rr = 0; rr < 4; ++rr) {
    int r = rb + rr * 8;
    dst[(size_t)r * K + c] = __float2bfloat16(tile[c][r]);
  }
}

// ---------------------------------------------------------------------------
// LayerNorm: x fp32 [NTOK][DIM] -> h bf16. One block (256 thr) per row.
// ---------------------------------------------------------------------------
__global__ __launch_bounds__(256) void ln_kernel(
    const float* __restrict__ x, const float* __restrict__ g,
    const float* __restrict__ b, bf16* __restrict__ h)
{
  const int row = blockIdx.x;
  const int tid = threadIdx.x;
  const float4 xv = *(const float4*)(x + (size_t)row * DIM + tid * 4);
  float s  = xv.x + xv.y + xv.z + xv.w;
  float s2 = xv.x * xv.x + xv.y * xv.y + xv.z * xv.z + xv.w * xv.w;
#pragma unroll
  for (int off = 1; off < 64; off <<= 1) {
    s  += __shfl_xor(s, off);
    s2 += __shfl_xor(s2, off);
  }
  __shared__ float red[8];
  const int wave = tid >> 6, lane = tid & 63;
  if (lane == 0) { red[wave * 2] = s; red[wave * 2 + 1] = s2; }
  __syncthreads();
  const float ts  = red[0] + red[2] + red[4] + red[6];
  const float ts2 = red[1] + red[3] + red[5] + red[7];
  const float mu  = ts * (1.0f / DIM);
  const float var = ts2 * (1.0f / DIM) - mu * mu;
  const float rstd = rsqrtf(var + 1e-5f);
  const float4 gv = *(const float4*)(g + tid * 4);
  const float4 bv = *(const float4*)(b + tid * 4);
  bf16 hv[4];
  hv[0] = __float2bfloat16((xv.x - mu) * rstd * gv.x + bv.x);
  hv[1] = __float2bfloat16((xv.y - mu) * rstd * gv.y + bv.y);
  hv[2] = __float2bfloat16((xv.z - mu) * rstd * gv.z + bv.z);
  hv[3] = __float2bfloat16((xv.w - mu) * rstd * gv.w + bv.w);
  *(uint2*)(h + (size_t)row * DIM + tid * 4) = *(uint2*)hv;
}

// ---------------------------------------------------------------------------
// gemm_t: 128xBN tile, 4 waves, single-buffer loop (replay-proven). Used for
// proj/FFN2 (BN=64, 2 blocks/CU). SWZ: bijective XCD swizzle (nwg%8==0).
// ---------------------------------------------------------------------------
template<int EPI, bool SWZ, int BN>
__global__ __launch_bounds__(256) void gemm_t(
    const bf16* __restrict__ A, const bf16* __restrict__ Bt,
    int N, int K,
    const float* __restrict__ bias,
    float* __restrict__ outf, bf16* __restrict__ outb,
    bf16* __restrict__ outq, bf16* __restrict__ outk, bf16* __restrict__ outvt)
{
  constexpr int NW = BN / 32;
  __shared__ alignas(16) bf16 As[128 * 64];
  __shared__ alignas(16) bf16 Bs[BN * 64];
  const int tid  = threadIdx.x;
  const int lane = tid & 63;
  const int wave = tid >> 6;
  const int wr = wave >> 1, wc = wave & 1;

  int bx, by;
  if (SWZ) {
    const int gx   = (int)gridDim.x;
    const int nwg  = gx * (int)gridDim.y;
    const int wg   = blockIdx.x + blockIdx.y * gx;
    const int xcd  = wg & 7;
    const int slot = wg >> 3;
    const int id   = xcd * (nwg >> 3) + slot;
    by = id / gx;
    bx = id % gx;
  } else {
    bx = blockIdx.x; by = blockIdx.y;
  }
  const int m0 = by * 128, n0 = bx * BN;
  const int sr = tid >> 3, pc = tid & 7;
  const int wbase = (tid & ~63) << 4;

  f32x4 acc[4][NW];
#pragma unroll
  for (int m = 0; m < 4; ++m)
#pragma unroll
    for (int n = 0; n < NW; ++n) acc[m][n] = (f32x4){0.f, 0.f, 0.f, 0.f};

  for (int k0 = 0; k0 < K; k0 += 64) {
#pragma unroll
    for (int it = 0; it < 4; ++it) {
      const int r  = it * 32 + sr;
      const int lc = pc ^ (r & 7);
      gld_lds16(A + (size_t)(m0 + r) * K + k0 + lc * 8, (char*)As + it * 4096 + wbase);
    }
#pragma unroll
    for (int it = 0; it < NW; ++it) {
      const int r  = it * 32 + sr;
      const int lc = pc ^ (r & 7);
      gld_lds16(Bt + (size_t)(n0 + r) * K + k0 + lc * 8, (char*)Bs + it * 4096 + wbase);
    }
    __syncthreads();
#pragma unroll
    for (int kk = 0; kk < 2; ++kk) {
      const int cb = kk * 4 + (lane >> 4);
      bf16x8 af[4], bfr[NW];
#pragma unroll
      for (int m = 0; m < 4; ++m) {
        const int r = wr * 64 + m * 16 + (lane & 15);
        af[m] = *(const bf16x8*)((const char*)As + r * 128 + ((cb ^ (r & 7)) << 4));
      }
#pragma unroll
      for (int n = 0; n < NW; ++n) {
        const int r = wc * (BN / 2) + n * 16 + (lane & 15);
        bfr[n] = *(const bf16x8*)((const char*)Bs + r * 128 + ((cb ^ (r & 7)) << 4));
      }
#pragma unroll
      for (int m = 0; m < 4; ++m)
#pragma unroll
        for (int n = 0; n < NW; ++n)
          acc[m][n] = __builtin_amdgcn_mfma_f32_16x16x32_bf16(af[m], bfr[n], acc[m][n], 0, 0, 0);
    }
    __syncthreads();
  }

#pragma unroll
  for (int m = 0; m < 4; ++m) {
    const int rb = m0 + wr * 64 + m * 16 + ((lane >> 4) << 2);
#pragma unroll
    for (int n = 0; n < NW; ++n) {
      const int col = n0 + wc * (BN / 2) + n * 16 + (lane & 15);
#pragma unroll
      for (int j = 0; j < 4; ++j) {
        const int row = rb + j;
        const float v = acc[m][n][j];
        if (EPI == 1) {
          const size_t off = (size_t)row * N + col;
          outf[off] = v + bias[col] + outf[off];
        } else if (EPI == 2) {
          const float t = v + bias[col];
          const float gg = 0.5f * t * (1.0f + erff(t * 0.70710678118654752f));
          outb[(size_t)row * N + col] = __float2bfloat16(gg);
        }
      }
    }
  }
}

// ---------------------------------------------------------------------------
// gemm256: 256x128 tile, BK=64, 8 waves (512 thr, 4x2 wave grid), NBUF=3
// depth-2 prefetch with COUNTED vmcnt (T3/T4): iter t issues stage(t+2) into
// buf[(t+2)%3] (6 loads/thread), computes tile t, then vmcnt(6) (own tile-t+1
// loads landed, tile-t+2's 6 stay in flight) + s_barrier (each wave verified
// its own loads BEFORE the barrier -> after it, all waves' loads visible).
// Buffer t is next written by tile t+3, issued after the end-of-iter-t
// barrier -> no overlap. Per-wave compute/epilogue identical to gemm_t's 4x4
// fragment scheme (row bases wr*64 of 256, wc*64 of 128). LDS 144KB ->
// 1 block/CU; 2 waves/SIMD + 12 loads in flight supply the overlap.
// For >=1-block/CU grids with K>=192: QKV (EPI 0) and FFN1 (EPI 2).
// ---------------------------------------------------------------------------
template<int EPI, bool SWZ>
__global__ __launch_bounds__(512) void gemm256(
    const bf16* __restrict__ A, const bf16* __restrict__ Bt,
    int N, int K,
    const float* __restrict__ bias,
    float* __restrict__ outf, bf16* __restrict__ outb,
    bf16* __restrict__ outq, bf16* __restrict__ outk, bf16* __restrict__ outvt)
{
  __shared__ alignas(16) bf16 As[3][256 * 64];
  __shared__ alignas(16) bf16 Bs[3][128 * 64];
  const int tid  = threadIdx.x;
  const int lane = tid & 63;
  const int wave = tid >> 6;       // 0..7
  const int wr = wave >> 1;        // 0..3 -> rows wr*64
  const int wc = wave & 1;         // 0..1 -> cols wc*64

  int bx, by;
  if (SWZ) {
    const int gx   = (int)gridDim.x;
    const int nwg  = gx * (int)gridDim.y;
    const int wg   = blockIdx.x + blockIdx.y * gx;
    const int xcd  = wg & 7;
    const int slot = wg >> 3;
    const int id   = xcd * (nwg >> 3) + slot;
    by = id / gx;
    bx = id % gx;
  } else {
    bx = blockIdx.x; by = blockIdx.y;
  }
  const int m0 = by * 256, n0 = bx * 128;
  const int sr = tid >> 3, pc = tid & 7;   // sr 0..63

  f32x4 acc[4][4];
#pragma unroll
  for (int m = 0; m < 4; ++m)
#pragma unroll
    for (int n = 0; n < 4; ++n) acc[m][n] = (f32x4){0.f, 0.f, 0.f, 0.f};

  // stage K-tile kt into buffer b: A 4x64 rows, B 2x64 rows; 6 loads/thread
  auto stage = [&](int kt, int b) {
    const int k0 = kt << 6;
#pragma unroll
    for (int it = 0; it < 4; ++it) {
      const int r  = it * 64 + sr;
      const int lc = pc ^ (sr & 7);
      gld_lds16(A + (size_t)(m0 + r) * K + k0 + lc * 8,
                (char*)&As[b][0] + it * 8192 + tid * 16);
    }
#pragma unroll
    for (int it = 0; it < 2; ++it) {
      const int r  = it * 64 + sr;
      const int lc = pc ^ (sr & 7);
      gld_lds16(Bt + (size_t)(n0 + r) * K + k0 + lc * 8,
                (char*)&Bs[b][0] + it * 8192 + tid * 16);
    }
  };

  auto compute = [&](int b) {
#pragma unroll
    for (int kk = 0; kk < 2; ++kk) {
      const int cb = kk * 4 + (lane >> 4);
      bf16x8 af[4], bfr[4];
#pragma unroll
      for (int m = 0; m < 4; ++m) {
        const int r = wr * 64 + m * 16 + (lane & 15);
        af[m] = *(const bf16x8*)((const char*)&As[b][0] + r * 128 + ((cb ^ (r & 7)) << 4));
      }
#pragma unroll
      for (int n = 0; n < 4; ++n) {
        const int r = wc * 64 + n * 16 + (lane & 15);
        bfr[n] = *(const bf16x8*)((const char*)&Bs[b][0] + r * 128 + ((cb ^ (r & 7)) << 4));
      }
      __builtin_amdgcn_s_setprio(1);
#pragma unroll
      for (int m = 0; m < 4; ++m)
#pragma unroll
        for (int n = 0; n < 4; ++n)
          acc[m][n] = __builtin_amdgcn_mfma_f32_16x16x32_bf16(af[m], bfr[n], acc[m][n], 0, 0, 0);
      __builtin_amdgcn_s_setprio(0);
    }
  };

  const int nt = K >> 6;   // >= 3
  stage(0, 0);
  stage(1, 1);
  asm volatile("s_waitcnt vmcnt(6)" ::: "memory");   // own tile-0 landed
  __builtin_amdgcn_s_barrier();                       // -> all waves' tile-0 landed
  int cur = 0;
  for (int t = 0; t < nt; ++t) {
    const int nxt2 = (cur + 2 >= 3) ? cur - 1 : cur + 2;
    if (t + 2 < nt) {
      stage(t + 2, nxt2);
      compute(cur);
      asm volatile("s_waitcnt vmcnt(6)" ::: "memory"); // own tile t+1 landed
    } else {
      compute(cur);
      asm volatile("s_waitcnt vmcnt(0)" ::: "memory"); // tail: drain
    }
    __builtin_amdgcn_s_barrier();
    cur = (cur + 1 == 3) ? 0 : cur + 1;
  }

#pragma unroll
  for (int m = 0; m < 4; ++m) {
    const int rb = m0 + wr * 64 + m * 16 + ((lane >> 4) << 2);
#pragma unroll
    for (int n = 0; n < 4; ++n) {
      const int col = n0 + wc * 64 + n * 16 + (lane & 15);
      if (EPI == 0 && col >= 2048) {
        const int batch = rb >> 11, tok = rb & 2047;
        const int c = col - 2048;
        union { bf16x4 v4; short s[4]; } w;
#pragma unroll
        for (int j = 0; j < 4; ++j) {
          const bf16 bb = __float2bfloat16(acc[m][n][j]);
          w.s[j] = *(const short*)&bb;
        }
        *(bf16x4*)(outvt + (((size_t)(batch * HEADS + (c >> 6))) * DIMH + (c & 63)) * SEQ + tok)
            = w.v4;
        continue;
      }
#pragma unroll
      for (int j = 0; j < 4; ++j) {
        const int row = rb + j;
        const float v = acc[m][n][j];
        if (EPI == 0) {
          const int batch = row >> 11, tok = row & 2047;
          if (col < 1024) {
            outq[(((size_t)(batch * HEADS + (col >> 6))) * SEQ + tok) * DIMH + (col & 63)] =
                __float2bfloat16(v * CS);
          } else {
            const int c = col - 1024;
            outk[(((size_t)(batch * HEADS + (c >> 6))) * SEQ + tok) * DIMH + (c & 63)] =
                __float2bfloat16(v);
          }
        } else if (EPI == 2) {
          const float t = v + bias[col];
          const float gg = 0.5f * t * (1.0f + erff(t * 0.70710678118654752f));
          outb[(size_t)row * N + col] = __float2bfloat16(gg);
        }
      }
    }
  }
}

// ---------------------------------------------------------------------------
// Flash attention (round-11 replay-proven). QBLK=128, KVBLK=128 (2 subtiles),
// double-buffered staging w/ counted vmcnt; static-max softmax; O^T=mfma(V^T,P).
// ---------------------------------------------------------------------------
__global__ __launch_bounds__(256) void attn_kernel(
    const bf16* __restrict__ q, const bf16* __restrict__ k,
    const bf16* __restrict__ vt, bf16* __restrict__ out)
{
  __shared__ alignas(16) bf16 Ks[2][2][64 * 64];
  __shared__ alignas(16) bf16 Vs[2][2][64 * 64];
  const int tid  = threadIdx.x;
  const int lane = tid & 63;
  const int wave = tid >> 6;
  const int g    = lane >> 4;
  const int lm   = lane & 15;
  const int bh   = blockIdx.y;
  const int qw   = blockIdx.x * 128 + wave * 32;
  const int sr = tid >> 3, pc = tid & 7;
  const int wbase = (tid & ~63) << 4;

  bf16x8 qf[2][2];
#pragma unroll
  for (int m = 0; m < 2; ++m)
#pragma unroll
    for (int kk = 0; kk < 2; ++kk)
      qf[m][kk] = *(const bf16x8*)(q + ((size_t)bh * SEQ + qw + m * 16 + lm) * DIMH
                                   + kk * 32 + g * 8);

  f32x4 ao[2][4];
#pragma unroll
  for (int m = 0; m < 2; ++m)
#pragma unroll
    for (int n = 0; n < 4; ++n) ao[m][n] = (f32x4){0.f, 0.f, 0.f, 0.f};
  float lrow[2] = {0.f, 0.f};

  auto stage = [&](int jt2, int buf) {
#pragma unroll
    for (int sub = 0; sub < 2; ++sub) {
      const int jt = jt2 * 2 + sub;
#pragma unroll
      for (int it = 0; it < 2; ++it) {
        const int r  = it * 32 + sr;
        const int lc = pc ^ (r & 7);
        gld_lds16(k  + ((size_t)bh * SEQ + jt * 64 + r) * DIMH + lc * 8,
                  (char*)&Ks[buf][sub][0] + it * 4096 + wbase);
        gld_lds16(vt + ((size_t)bh * DIMH + r) * SEQ + jt * 64 + lc * 8,
                  (char*)&Vs[buf][sub][0] + it * 4096 + wbase);
      }
    }
  };

  stage(0, 0);
  __syncthreads();

  for (int jt2 = 0; jt2 < SEQ / 128; ++jt2) {
    const int buf = jt2 & 1;
    const bool pref = (jt2 + 1 < SEQ / 128);
    if (pref) {
      stage(jt2 + 1, buf ^ 1);
      asm volatile("s_waitcnt vmcnt(8)" ::: "memory");
    } else {
      asm volatile("s_waitcnt vmcnt(0)" ::: "memory");
    }

#pragma unroll
    for (int sub = 0; sub < 2; ++sub) {
      f32x4 sa[2][4];
#pragma unroll
      for (int m = 0; m < 2; ++m)
#pragma unroll
        for (int n = 0; n < 4; ++n)
          sa[m][n] = (f32x4){-SMAX, -SMAX, -SMAX, -SMAX};
      __builtin_amdgcn_s_setprio(1);
#pragma unroll
      for (int kk = 0; kk < 2; ++kk)
#pragma unroll
        for (int n = 0; n < 4; ++n) {
          const int row = n * 16 + lm;
          const bf16x8 af = *(const bf16x8*)((const char*)&Ks[buf][sub][0] + row * 128
                                             + (((kk * 4 + g) ^ (row & 7)) << 4));
#pragma unroll
          for (int m = 0; m < 2; ++m)
            sa[m][n] = __builtin_amdgcn_mfma_f32_16x16x32_bf16(af, qf[m][kk], sa[m][n], 0, 0, 0);
        }
      __builtin_amdgcn_s_setprio(0);

      bf16x8 pa[2][2];
#pragma unroll
      for (int m = 0; m < 2; ++m) {
        float rs = 0.f;
#pragma unroll
        for (int n = 0; n < 4; ++n)
#pragma unroll
          for (int r = 0; r < 4; ++r) {
            const float p = exp2f(sa[m][n][r]);
            sa[m][n][r] = p;
            rs += p;
          }
        rs += __shfl_xor(rs, 16);
        rs += __shfl_xor(rs, 32);
        lrow[m] += rs;
#pragma unroll
        for (int h = 0; h < 2; ++h) {
          union { bf16x8 v8; short s[8]; } u;
#pragma unroll
          for (int n2 = 0; n2 < 2; ++n2)
#pragma unroll
            for (int r = 0; r < 4; ++r) {
              const bf16 bb = __float2bfloat16(sa[m][h * 2 + n2][r]);
              u.s[n2 * 4 + r] = *(const short*)&bb;
            }
          pa[m][h] = u.v8;
        }
      }

      __builtin_amdgcn_s_setprio(1);
#pragma unroll
      for (int n = 0; n < 4; ++n) {
        const int row = n * 16 + lm;
        const char* vb = (const char*)&Vs[buf][sub][0] + row * 128;
        const int sw = row & 7;
#pragma unroll
        for (int kk = 0; kk < 2; ++kk) {
          const bf16x4 lo = *(const bf16x4*)(vb + (((kk * 4 + (g >> 1)) ^ sw) << 4) + (g & 1) * 8);
          const bf16x4 hi = *(const bf16x4*)(vb + (((kk * 4 + 2 + (g >> 1)) ^ sw) << 4) + (g & 1) * 8);
          const bf16x8 vf = __builtin_shufflevector(lo, hi, 0, 1, 2, 3, 4, 5, 6, 7);
#pragma unroll
          for (int m = 0; m < 2; ++m)
            ao[m][n] = __builtin_amdgcn_mfma_f32_16x16x32_bf16(vf, pa[m][kk], ao[m][n], 0, 0, 0);
        }
      }
      __builtin_amdgcn_s_setprio(0);
    }
    __builtin_amdgcn_s_barrier();
  }

  const int batch = bh >> 4, head = bh & 15;
#pragma unroll
  for (int m = 0; m < 2; ++m) {
    const float linv = 1.0f / lrow[m];
    const int row = qw + m * 16 + lm;
    bf16* orow = out + ((size_t)batch * SEQ + row) * INNER + head * DIMH;
#pragma unroll
    for (int n = 0; n < 4; ++n) {
      union { bf16x4 v4; short s[4]; } w;
#pragma unroll
      for (int r = 0; r < 4; ++r) {
        const bf16 bb = __float2bfloat16(ao[m][n][r] * linv);
        w.s[r] = *(const short*)&bb;
      }
      *(bf16x4*)(orow + n * 16 + g * 4) = w.v4;
    }
  }
}

// ---------------------------------------------------------------------------
extern "C" void kernel_launch(void* const* d_in, const int* in_sizes, int n_in,
                              void* d_out, int out_size, void* d_ws, size_t ws_size,
                              hipStream_t stream)
{
  (void)in_sizes; (void)n_in; (void)out_size; (void)ws_size;
  const float* x_in = (const float*)d_in[0];
  const float* Wq   = (const float*)d_in[1];
  const float* Wkv  = (const float*)d_in[2];
  const float* Wo   = (const float*)d_in[3];
  const float* bo   = (const float*)d_in[4];
  const float* ln1g = (const float*)d_in[5];
  const float* ln1b = (const float*)d_in[6];
  const float* ln2g = (const float*)d_in[7];
  const float* ln2b = (const float*)d_in[8];
  const float* W1   = (const float*)d_in[9];
  const float* b1   = (const float*)d_in[10];
  const float* W2   = (const float*)d_in[11];
  const float* b2   = (const float*)d_in[12];
  float* xb = (float*)d_out;

  char* ws = (char*)d_ws;
  size_t off = 0;
  auto take = [&](size_t bytes) {
    char* p = ws + off;
    off += (bytes + 255) & ~(size_t)255;
    return p;
  };
  bf16* Wqkvt = (bf16*)take((size_t)DEPTH * 3072 * 1024 * 2);
  bf16* Wot   = (bf16*)take((size_t)DEPTH * 1024 * 1024 * 2);
  bf16* W1t   = (bf16*)take((size_t)DEPTH * 4096 * 1024 * 2);
  bf16* W2t   = (bf16*)take((size_t)DEPTH * 1024 * 4096 * 2);
  bf16* hb    = (bf16*)take((size_t)NTOK * DIM * 2);
  bf16* qbuf  = (bf16*)take((size_t)NTOK * INNER * 2);
  bf16* kbuf  = (bf16*)take((size_t)NTOK * INNER * 2);
  bf16* vtbuf = (bf16*)take((size_t)NTOK * INNER * 2);
  bf16* aobuf = (bf16*)take((size_t)NTOK * INNER * 2);
  bf16* h1buf = (bf16*)take((size_t)NTOK * DFF * 2);

  hipMemcpyAsync(xb, x_in, (size_t)NTOK * DIM * 4, hipMemcpyDeviceToDevice, stream);

  dim3 b256(256);
  dim3 b512(512);
  transpose_convert<<<dim3(32, 32, DEPTH),  b256, 0, stream>>>(Wq,  Wqkvt, 1024, 1024, 0,    3072);
  transpose_convert<<<dim3(64, 32, DEPTH),  b256, 0, stream>>>(Wkv, Wqkvt, 1024, 2048, 1024, 3072);
  transpose_convert<<<dim3(32, 32, DEPTH),  b256, 0, stream>>>(Wo,  Wot,   1024, 1024, 0,    1024);
  transpose_convert<<<dim3(128, 32, DEPTH), b256, 0, stream>>>(W1,  W1t,   1024, 4096, 0,    4096);
  transpose_convert<<<dim3(32, 128, DEPTH), b256, 0, stream>>>(W2,  W2t,   4096, 1024, 0,    1024);

  for (int l = 0; l < DEPTH; ++l) {
    ln_kernel<<<NTOK, b256, 0, stream>>>(xb, ln1g + l * DIM, ln1b + l * DIM, hb);
    gemm256<0, true><<<dim3(3072 / 128, NTOK / 256), b512, 0, stream>>>(
        hb, Wqkvt + (size_t)l * 3072 * 1024, 3072, 1024,
        nullptr, nullptr, nullptr, qbuf, kbuf, vtbuf);
    attn_kernel<<<dim3(SEQ / 128, 32), b256, 0, stream>>>(qbuf, kbuf, vtbuf, aobuf);
    gemm_t<1, true, 64><<<dim3(1024 / 64, NTOK / 128), b256, 0, stream>>>(
        aobuf, Wot + (size_t)l * 1024 * 1024, 1024, 1024,
        bo + l * DIM, xb, nullptr, nullptr, nullptr, nullptr);
    ln_kernel<<<NTOK, b256, 0, stream>>>(xb, ln2g + l * DIM, ln2b + l * DIM, hb);
    gemm256<2, true><<<dim3(4096 / 128, NTOK / 256), b512, 0, stream>>>(
        hb, W1t + (size_t)l * 4096 * 1024, 4096, 1024,
        b1 + l * DFF, nullptr, h1buf, nullptr, nullptr, nullptr);
    gemm_t<1, true, 64><<<dim3(1024 / 64, NTOK / 128), b256, 0, stream>>>(
        h1buf, W2t + (size_t)l * 1024 * 4096, 1024, 4096,
        b2 + l * DIM, xb, nullptr, nullptr, nullptr, nullptr);
  }
}

// Round 13
// 1686.187 us; speedup vs baseline: 1.1314x; 1.1314x over previous
//
#include <hip/hip_runtime.h>
#include <hip/hip_bf16.h>
#include <cstdint>
#include <cstddef>

#define DEPTH 6
#define DIM   1024
#define HEADS 16
#define DIMH  64
#define INNER 1024
#define DFF   4096
#define SEQ   2048
#define NTOK  4096   // 2 * 2048

typedef __attribute__((ext_vector_type(8))) short bf16x8;
typedef __attribute__((ext_vector_type(4))) short bf16x4;
typedef __attribute__((ext_vector_type(4))) float f32x4;
typedef __hip_bfloat16 bf16;

#define CS 0.18033688011112042f  // SCALE * log2(e)
#define SMAX 24.0f               // static softmax max (exp2 domain)

__device__ __forceinline__ void gld_lds16(const void* g, void* l) {
  __builtin_amdgcn_global_load_lds(
      (const __attribute__((address_space(1))) unsigned int*)g,
      (__attribute__((address_space(3))) unsigned int*)l,
      16, 0, 0);
}

// ---------------------------------------------------------------------------
// Weight transpose + fp32->bf16 convert: in [D][K][N] -> out [D][orows][K]
// ---------------------------------------------------------------------------
__global__ __launch_bounds__(256) void transpose_convert(
    const float* __restrict__ in, bf16* __restrict__ out,
    int K, int N, int row0, int orows)
{
  __shared__ float tile[32][33];
  const int d  = blockIdx.z;
  const int n0 = blockIdx.x * 32, k0 = blockIdx.y * 32;
  const int c = threadIdx.x & 31, rb = threadIdx.x >> 5;
  const float* src = in + ((size_t)d * K + k0) * N + n0;
#pragma unroll
  for (int rr = 0; rr < 4; ++rr) {
    int r = rb + rr * 8;
    tile[r][c] = src[(size_t)r * N + c];
  }
  __syncthreads();
  bf16* dst = out + ((size_t)d * orows + row0 + n0) * K + k0;
#pragma unroll
  for (int rr = 0; rr < 4; ++rr) {
    int r = rb + rr * 8;
    dst[(size_t)r * K + c] = __float2bfloat16(tile[c][r]);
  }
}

// ---------------------------------------------------------------------------
// LayerNorm: x fp32 [NTOK][DIM] -> h bf16. One block (256 thr) per row.
// ---------------------------------------------------------------------------
__global__ __launch_bounds__(256) void ln_kernel(
    const float* __restrict__ x, const float* __restrict__ g,
    const float* __restrict__ b, bf16* __restrict__ h)
{
  const int row = blockIdx.x;
  const int tid = threadIdx.x;
  const float4 xv = *(const float4*)(x + (size_t)row * DIM + tid * 4);
  float s  = xv.x + xv.y + xv.z + xv.w;
  float s2 = xv.x * xv.x + xv.y * xv.y + xv.z * xv.z + xv.w * xv.w;
#pragma unroll
  for (int off = 1; off < 64; off <<= 1) {
    s  += __shfl_xor(s, off);
    s2 += __shfl_xor(s2, off);
  }
  __shared__ float red[8];
  const int wave = tid >> 6, lane = tid & 63;
  if (lane == 0) { red[wave * 2] = s; red[wave * 2 + 1] = s2; }
  __syncthreads();
  const float ts  = red[0] + red[2] + red[4] + red[6];
  const float ts2 = red[1] + red[3] + red[5] + red[7];
  const float mu  = ts * (1.0f / DIM);
  const float var = ts2 * (1.0f / DIM) - mu * mu;
  const float rstd = rsqrtf(var + 1e-5f);
  const float4 gv = *(const float4*)(g + tid * 4);
  const float4 bv = *(const float4*)(b + tid * 4);
  bf16 hv[4];
  hv[0] = __float2bfloat16((xv.x - mu) * rstd * gv.x + bv.x);
  hv[1] = __float2bfloat16((xv.y - mu) * rstd * gv.y + bv.y);
  hv[2] = __float2bfloat16((xv.z - mu) * rstd * gv.z + bv.z);
  hv[3] = __float2bfloat16((xv.w - mu) * rstd * gv.w + bv.w);
  *(uint2*)(h + (size_t)row * DIM + tid * 4) = *(uint2*)hv;
}

// ---------------------------------------------------------------------------
// GEMM: C[M,N] = A[M,K](bf16,row-major) x Bt[N,K](bf16, = B^T).
// 128xBN tile, BK=64, 4 waves (2x2), 16x16x32 MFMA, global_load_lds + XOR
// swizzle. Single-buffer stage->sync->compute->sync loop (replay-proven;
// round-11 configuration restored — gemm256 coarse pipeline regressed).
// SWZ: bijective XCD swizzle (nwg%8==0).
// EPI 0: QKV split (q pre-scaled by CS; vt stores vectorized 8B over j);
// EPI 1: +bias+residual fp32; EPI 2: bf16 gelu.
// ---------------------------------------------------------------------------
template<int EPI, bool SWZ, int BN>
__global__ __launch_bounds__(256) void gemm_t(
    const bf16* __restrict__ A, const bf16* __restrict__ Bt,
    int N, int K,
    const float* __restrict__ bias,
    float* __restrict__ outf, bf16* __restrict__ outb,
    bf16* __restrict__ outq, bf16* __restrict__ outk, bf16* __restrict__ outvt)
{
  constexpr int NW = BN / 32;
  __shared__ alignas(16) bf16 As[128 * 64];
  __shared__ alignas(16) bf16 Bs[BN * 64];
  const int tid  = threadIdx.x;
  const int lane = tid & 63;
  const int wave = tid >> 6;
  const int wr = wave >> 1, wc = wave & 1;

  int bx, by;
  if (SWZ) {
    const int gx   = (int)gridDim.x;
    const int nwg  = gx * (int)gridDim.y;
    const int wg   = blockIdx.x + blockIdx.y * gx;
    const int xcd  = wg & 7;
    const int slot = wg >> 3;
    const int id   = xcd * (nwg >> 3) + slot;   // bijective (nwg%8==0)
    by = id / gx;
    bx = id % gx;
  } else {
    bx = blockIdx.x; by = blockIdx.y;
  }
  const int m0 = by * 128, n0 = bx * BN;
  const int sr = tid >> 3, pc = tid & 7;
  const int wbase = (tid & ~63) << 4;

  f32x4 acc[4][NW];
#pragma unroll
  for (int m = 0; m < 4; ++m)
#pragma unroll
    for (int n = 0; n < NW; ++n) acc[m][n] = (f32x4){0.f, 0.f, 0.f, 0.f};

  for (int k0 = 0; k0 < K; k0 += 64) {
#pragma unroll
    for (int it = 0; it < 4; ++it) {
      const int r  = it * 32 + sr;
      const int lc = pc ^ (r & 7);
      gld_lds16(A + (size_t)(m0 + r) * K + k0 + lc * 8, (char*)As + it * 4096 + wbase);
    }
#pragma unroll
    for (int it = 0; it < NW; ++it) {
      const int r  = it * 32 + sr;
      const int lc = pc ^ (r & 7);
      gld_lds16(Bt + (size_t)(n0 + r) * K + k0 + lc * 8, (char*)Bs + it * 4096 + wbase);
    }
    __syncthreads();
#pragma unroll
    for (int kk = 0; kk < 2; ++kk) {
      const int cb = kk * 4 + (lane >> 4);
      bf16x8 af[4], bfr[NW];
#pragma unroll
      for (int m = 0; m < 4; ++m) {
        const int r = wr * 64 + m * 16 + (lane & 15);
        af[m] = *(const bf16x8*)((const char*)As + r * 128 + ((cb ^ (r & 7)) << 4));
      }
#pragma unroll
      for (int n = 0; n < NW; ++n) {
        const int r = wc * (BN / 2) + n * 16 + (lane & 15);
        bfr[n] = *(const bf16x8*)((const char*)Bs + r * 128 + ((cb ^ (r & 7)) << 4));
      }
#pragma unroll
      for (int m = 0; m < 4; ++m)
#pragma unroll
        for (int n = 0; n < NW; ++n)
          acc[m][n] = __builtin_amdgcn_mfma_f32_16x16x32_bf16(af[m], bfr[n], acc[m][n], 0, 0, 0);
    }
    __syncthreads();
  }

#pragma unroll
  for (int m = 0; m < 4; ++m) {
    const int rb = m0 + wr * 64 + m * 16 + ((lane >> 4) << 2);
#pragma unroll
    for (int n = 0; n < NW; ++n) {
      const int col = n0 + wc * (BN / 2) + n * 16 + (lane & 15);
      if (EPI == 0 && col >= 2048) {
        // vt store: 4 consecutive tok at fixed d-col -> one 8B store
        const int batch = rb >> 11, tok = rb & 2047;
        const int c = col - 2048;
        union { bf16x4 v4; short s[4]; } w;
#pragma unroll
        for (int j = 0; j < 4; ++j) {
          const bf16 bb = __float2bfloat16(acc[m][n][j]);
          w.s[j] = *(const short*)&bb;
        }
        *(bf16x4*)(outvt + (((size_t)(batch * HEADS + (c >> 6))) * DIMH + (c & 63)) * SEQ + tok)
            = w.v4;
        continue;
      }
#pragma unroll
      for (int j = 0; j < 4; ++j) {
        const int row = rb + j;
        const float v = acc[m][n][j];
        if (EPI == 0) {
          const int batch = row >> 11, tok = row & 2047;
          if (col < 1024) {
            outq[(((size_t)(batch * HEADS + (col >> 6))) * SEQ + tok) * DIMH + (col & 63)] =
                __float2bfloat16(v * CS);
          } else {
            const int c = col - 1024;
            outk[(((size_t)(batch * HEADS + (c >> 6))) * SEQ + tok) * DIMH + (c & 63)] =
                __float2bfloat16(v);
          }
        } else if (EPI == 1) {
          const size_t off = (size_t)row * N + col;
          outf[off] = v + bias[col] + outf[off];
        } else if (EPI == 2) {
          const float t = v + bias[col];
          const float gg = 0.5f * t * (1.0f + erff(t * 0.70710678118654752f));
          outb[(size_t)row * N + col] = __float2bfloat16(gg);
        }
      }
    }
  }
}

// ---------------------------------------------------------------------------
// Flash attention. 8 waves x 32 q-rows (QBLK=256, 512 thr), KVBLK=128 (two
// 64-kv subtiles per buffer), double-buffered. Staging = 4 gld_lds/thread
// per tile (one instruction per 8KB subtile at 512 threads) — half the
// staging work per unit output vs QBLK=128. Counted-vmcnt with CORRECT
// cross-wave ordering: stage(next); vmcnt(4) [own current-tile loads
// landed]; s_barrier [-> ALL waves' current-tile loads landed; next tile's
// loads stay in flight]; compute; s_barrier [readers done before next
// stage overwrites].
// STATIC-MAX softmax (acc init -SMAX, p = exp2(sa), no max chain/rescale).
// S^T = mfma(K, Q): q lane-local. O^T = mfma(V^T, P): zero-shuffle epilogue,
// 8B stores. Q pre-scaled by CS.
// ---------------------------------------------------------------------------
__global__ __launch_bounds__(512) void attn_kernel(
    const bf16* __restrict__ q, const bf16* __restrict__ k,
    const bf16* __restrict__ vt, bf16* __restrict__ out)
{
  __shared__ alignas(16) bf16 Ks[2][2][64 * 64];
  __shared__ alignas(16) bf16 Vs[2][2][64 * 64];
  const int tid  = threadIdx.x;
  const int lane = tid & 63;
  const int wave = tid >> 6;        // 0..7
  const int g    = lane >> 4;
  const int lm   = lane & 15;
  const int bh   = blockIdx.y;
  const int qw   = blockIdx.x * 256 + wave * 32;
  const int sr = tid >> 3, pc = tid & 7;   // sr 0..63, pc 0..7

  bf16x8 qf[2][2];
#pragma unroll
  for (int m = 0; m < 2; ++m)
#pragma unroll
    for (int kk = 0; kk < 2; ++kk)
      qf[m][kk] = *(const bf16x8*)(q + ((size_t)bh * SEQ + qw + m * 16 + lm) * DIMH
                                   + kk * 32 + g * 8);

  f32x4 ao[2][4];   // O^T: ao[m][n][r] = O[q=qw+m*16+lm][d = n*16 + g*4 + r]
#pragma unroll
  for (int m = 0; m < 2; ++m)
#pragma unroll
    for (int n = 0; n < 4; ++n) ao[m][n] = (f32x4){0.f, 0.f, 0.f, 0.f};
  float lrow[2] = {0.f, 0.f};

  // stage K/V for two consecutive 64-kv tiles: 4 loads/thread total.
  // Each 8KB subtile = one gld_lds16 across 512 threads (row sr, chunk pc,
  // XOR-swizzled source column; LDS dest = wave-uniform base + lane*16).
  const int lc = pc ^ (sr & 7);
  auto stage = [&](int jt2, int buf) {
#pragma unroll
    for (int sub = 0; sub < 2; ++sub) {
      const int jt = jt2 * 2 + sub;
      gld_lds16(k  + ((size_t)bh * SEQ + jt * 64 + sr) * DIMH + lc * 8,
                (char*)&Ks[buf][sub][0] + tid * 16);
      gld_lds16(vt + ((size_t)bh * DIMH + sr) * SEQ + jt * 64 + lc * 8,
                (char*)&Vs[buf][sub][0] + tid * 16);
    }
  };

  stage(0, 0);   // 4 loads in flight; certified by first-iteration vmcnt+barrier

  for (int jt2 = 0; jt2 < SEQ / 128; ++jt2) {
    const int buf = jt2 & 1;
    const bool pref = (jt2 + 1 < SEQ / 128);
    if (pref) {
      stage(jt2 + 1, buf ^ 1);
      asm volatile("s_waitcnt vmcnt(4)" ::: "memory");  // own tile-jt2 loads landed
    } else {
      asm volatile("s_waitcnt vmcnt(0)" ::: "memory");
    }
    __builtin_amdgcn_s_barrier();   // all waves' tile-jt2 landed; next in flight

#pragma unroll
    for (int sub = 0; sub < 2; ++sub) {
      f32x4 sa[2][4];
#pragma unroll
      for (int m = 0; m < 2; ++m)
#pragma unroll
        for (int n = 0; n < 4; ++n)
          sa[m][n] = (f32x4){-SMAX, -SMAX, -SMAX, -SMAX};
      __builtin_amdgcn_s_setprio(1);
#pragma unroll
      for (int kk = 0; kk < 2; ++kk)
#pragma unroll
        for (int n = 0; n < 4; ++n) {
          const int row = n * 16 + lm;
          const bf16x8 af = *(const bf16x8*)((const char*)&Ks[buf][sub][0] + row * 128
                                             + (((kk * 4 + g) ^ (row & 7)) << 4));
#pragma unroll
          for (int m = 0; m < 2; ++m)
            sa[m][n] = __builtin_amdgcn_mfma_f32_16x16x32_bf16(af, qf[m][kk], sa[m][n], 0, 0, 0);
        }
      __builtin_amdgcn_s_setprio(0);

      bf16x8 pa[2][2];
#pragma unroll
      for (int m = 0; m < 2; ++m) {
        float rs = 0.f;
#pragma unroll
        for (int n = 0; n < 4; ++n)
#pragma unroll
          for (int r = 0; r < 4; ++r) {
            const float p = exp2f(sa[m][n][r]);
            sa[m][n][r] = p;
            rs += p;
          }
        rs += __shfl_xor(rs, 16);
        rs += __shfl_xor(rs, 32);
        lrow[m] += rs;
#pragma unroll
        for (int h = 0; h < 2; ++h) {
          union { bf16x8 v8; short s[8]; } u;
#pragma unroll
          for (int n2 = 0; n2 < 2; ++n2)
#pragma unroll
            for (int r = 0; r < 4; ++r) {
              const bf16 bb = __float2bfloat16(sa[m][h * 2 + n2][r]);
              u.s[n2 * 4 + r] = *(const short*)&bb;
            }
          pa[m][h] = u.v8;
        }
      }

      __builtin_amdgcn_s_setprio(1);
#pragma unroll
      for (int n = 0; n < 4; ++n) {
        const int row = n * 16 + lm;
        const char* vb = (const char*)&Vs[buf][sub][0] + row * 128;
        const int sw = row & 7;
#pragma unroll
        for (int kk = 0; kk < 2; ++kk) {
          const bf16x4 lo = *(const bf16x4*)(vb + (((kk * 4 + (g >> 1)) ^ sw) << 4) + (g & 1) * 8);
          const bf16x4 hi = *(const bf16x4*)(vb + (((kk * 4 + 2 + (g >> 1)) ^ sw) << 4) + (g & 1) * 8);
          const bf16x8 vf = __builtin_shufflevector(lo, hi, 0, 1, 2, 3, 4, 5, 6, 7);
#pragma unroll
          for (int m = 0; m < 2; ++m)
            ao[m][n] = __builtin_amdgcn_mfma_f32_16x16x32_bf16(vf, pa[m][kk], ao[m][n], 0, 0, 0);
        }
      }
      __builtin_amdgcn_s_setprio(0);
    }
    __builtin_amdgcn_s_barrier();   // readers of buf done before next stage
  }

  const int batch = bh >> 4, head = bh & 15;
#pragma unroll
  for (int m = 0; m < 2; ++m) {
    const float linv = 1.0f / lrow[m];
    const int row = qw + m * 16 + lm;
    bf16* orow = out + ((size_t)batch * SEQ + row) * INNER + head * DIMH;
#pragma unroll
    for (int n = 0; n < 4; ++n) {
      union { bf16x4 v4; short s[4]; } w;
#pragma unroll
      for (int r = 0; r < 4; ++r) {
        const bf16 bb = __float2bfloat16(ao[m][n][r] * linv);
        w.s[r] = *(const short*)&bb;
      }
      *(bf16x4*)(orow + n * 16 + g * 4) = w.v4;
    }
  }
}

// ---------------------------------------------------------------------------
extern "C" void kernel_launch(void* const* d_in, const int* in_sizes, int n_in,
                              void* d_out, int out_size, void* d_ws, size_t ws_size,
                              hipStream_t stream)
{
  (void)in_sizes; (void)n_in; (void)out_size; (void)ws_size;
  const float* x_in = (const float*)d_in[0];
  const float* Wq   = (const float*)d_in[1];
  const float* Wkv  = (const float*)d_in[2];
  const float* Wo   = (const float*)d_in[3];
  const float* bo   = (const float*)d_in[4];
  const float* ln1g = (const float*)d_in[5];
  const float* ln1b = (const float*)d_in[6];
  const float* ln2g = (const float*)d_in[7];
  const float* ln2b = (const float*)d_in[8];
  const float* W1   = (const float*)d_in[9];
  const float* b1   = (const float*)d_in[10];
  const float* W2   = (const float*)d_in[11];
  const float* b2   = (const float*)d_in[12];
  float* xb = (float*)d_out;

  char* ws = (char*)d_ws;
  size_t off = 0;
  auto take = [&](size_t bytes) {
    char* p = ws + off;
    off += (bytes + 255) & ~(size_t)255;
    return p;
  };
  bf16* Wqkvt = (bf16*)take((size_t)DEPTH * 3072 * 1024 * 2);
  bf16* Wot   = (bf16*)take((size_t)DEPTH * 1024 * 1024 * 2);
  bf16* W1t   = (bf16*)take((size_t)DEPTH * 4096 * 1024 * 2);
  bf16* W2t   = (bf16*)take((size_t)DEPTH * 1024 * 4096 * 2);
  bf16* hb    = (bf16*)take((size_t)NTOK * DIM * 2);
  bf16* qbuf  = (bf16*)take((size_t)NTOK * INNER * 2);
  bf16* kbuf  = (bf16*)take((size_t)NTOK * INNER * 2);
  bf16* vtbuf = (bf16*)take((size_t)NTOK * INNER * 2);
  bf16* aobuf = (bf16*)take((size_t)NTOK * INNER * 2);
  bf16* h1buf = (bf16*)take((size_t)NTOK * DFF * 2);

  hipMemcpyAsync(xb, x_in, (size_t)NTOK * DIM * 4, hipMemcpyDeviceToDevice, stream);

  dim3 b256(256);
  dim3 b512(512);
  transpose_convert<<<dim3(32, 32, DEPTH),  b256, 0, stream>>>(Wq,  Wqkvt, 1024, 1024, 0,    3072);
  transpose_convert<<<dim3(64, 32, DEPTH),  b256, 0, stream>>>(Wkv, Wqkvt, 1024, 2048, 1024, 3072);
  transpose_convert<<<dim3(32, 32, DEPTH),  b256, 0, stream>>>(Wo,  Wot,   1024, 1024, 0,    1024);
  transpose_convert<<<dim3(128, 32, DEPTH), b256, 0, stream>>>(W1,  W1t,   1024, 4096, 0,    4096);
  transpose_convert<<<dim3(32, 128, DEPTH), b256, 0, stream>>>(W2,  W2t,   4096, 1024, 0,    1024);

  for (int l = 0; l < DEPTH; ++l) {
    ln_kernel<<<NTOK, b256, 0, stream>>>(xb, ln1g + l * DIM, ln1b + l * DIM, hb);
    gemm_t<0, true, 128><<<dim3(3072 / 128, NTOK / 128), b256, 0, stream>>>(
        hb, Wqkvt + (size_t)l * 3072 * 1024, 3072, 1024,
        nullptr, nullptr, nullptr, qbuf, kbuf, vtbuf);
    attn_kernel<<<dim3(SEQ / 256, 32), b512, 0, stream>>>(qbuf, kbuf, vtbuf, aobuf);
    gemm_t<1, true, 64><<<dim3(1024 / 64, NTOK / 128), b256, 0, stream>>>(
        aobuf, Wot + (size_t)l * 1024 * 1024, 1024, 1024,
        bo + l * DIM, xb, nullptr, nullptr, nullptr, nullptr);
    ln_kernel<<<NTOK, b256, 0, stream>>>(xb, ln2g + l * DIM, ln2b + l * DIM, hb);
    gemm_t<2, true, 128><<<dim3(4096 / 128, NTOK / 128), b256, 0, stream>>>(
        hb, W1t + (size_t)l * 4096 * 1024, 4096, 1024,
        b1 + l * DFF, nullptr, h1buf, nullptr, nullptr, nullptr);
    gemm_t<1, true, 64><<<dim3(1024 / 64, NTOK / 128), b256, 0, stream>>>(
        h1buf, W2t + (size_t)l * 1024 * 4096, 1024, 4096,
        b2 + l * DIM, xb, nullptr, nullptr, nullptr, nullptr);
  }
}

// Round 14
// 1531.775 us; speedup vs baseline: 1.2455x; 1.1008x over previous
//
#include <hip/hip_runtime.h>
#include <hip/hip_bf16.h>
#include <cstdint>
#include <cstddef>

#define DEPTH 6
#define DIM   1024
#define HEADS 16
#define DIMH  64
#define INNER 1024
#define DFF   4096
#define SEQ   2048
#define NTOK  4096   // 2 * 2048

typedef __attribute__((ext_vector_type(8))) short bf16x8;
typedef __attribute__((ext_vector_type(4))) short bf16x4;
typedef __attribute__((ext_vector_type(4))) float f32x4;
typedef __hip_bfloat16 bf16;

#define CS 0.18033688011112042f  // SCALE * log2(e)
#define SMAX 24.0f               // static softmax max (exp2 domain)

__device__ __forceinline__ void gld_lds16(const void* g, void* l) {
  __builtin_amdgcn_global_load_lds(
      (const __attribute__((address_space(1))) unsigned int*)g,
      (__attribute__((address_space(3))) unsigned int*)l,
      16, 0, 0);
}

// ---------------------------------------------------------------------------
// Weight transpose + fp32->bf16 convert: in [D][K][N] -> out [D][orows][K]
// ---------------------------------------------------------------------------
__global__ __launch_bounds__(256) void transpose_convert(
    const float* __restrict__ in, bf16* __restrict__ out,
    int K, int N, int row0, int orows)
{
  __shared__ float tile[32][33];
  const int d  = blockIdx.z;
  const int n0 = blockIdx.x * 32, k0 = blockIdx.y * 32;
  const int c = threadIdx.x & 31, rb = threadIdx.x >> 5;
  const float* src = in + ((size_t)d * K + k0) * N + n0;
#pragma unroll
  for (int rr = 0; rr < 4; ++rr) {
    int r = rb + rr * 8;
    tile[r][c] = src[(size_t)r * N + c];
  }
  __syncthreads();
  bf16* dst = out + ((size_t)d * orows + row0 + n0) * K + k0;
#pragma unroll
  for (int rr = 0; rr < 4; ++rr) {
    int r = rb + rr * 8;
    dst[(size_t)r * K + c] = __float2bfloat16(tile[c][r]);
  }
}

// ---------------------------------------------------------------------------
// LayerNorm: x fp32 [NTOK][DIM] -> h bf16. One block (256 thr) per row.
// ---------------------------------------------------------------------------
__global__ __launch_bounds__(256) void ln_kernel(
    const float* __restrict__ x, const float* __restrict__ g,
    const float* __restrict__ b, bf16* __restrict__ h)
{
  const int row = blockIdx.x;
  const int tid = threadIdx.x;
  const float4 xv = *(const float4*)(x + (size_t)row * DIM + tid * 4);
  float s  = xv.x + xv.y + xv.z + xv.w;
  float s2 = xv.x * xv.x + xv.y * xv.y + xv.z * xv.z + xv.w * xv.w;
#pragma unroll
  for (int off = 1; off < 64; off <<= 1) {
    s  += __shfl_xor(s, off);
    s2 += __shfl_xor(s2, off);
  }
  __shared__ float red[8];
  const int wave = tid >> 6, lane = tid & 63;
  if (lane == 0) { red[wave * 2] = s; red[wave * 2 + 1] = s2; }
  __syncthreads();
  const float ts  = red[0] + red[2] + red[4] + red[6];
  const float ts2 = red[1] + red[3] + red[5] + red[7];
  const float mu  = ts * (1.0f / DIM);
  const float var = ts2 * (1.0f / DIM) - mu * mu;
  const float rstd = rsqrtf(var + 1e-5f);
  const float4 gv = *(const float4*)(g + tid * 4);
  const float4 bv = *(const float4*)(b + tid * 4);
  bf16 hv[4];
  hv[0] = __float2bfloat16((xv.x - mu) * rstd * gv.x + bv.x);
  hv[1] = __float2bfloat16((xv.y - mu) * rstd * gv.y + bv.y);
  hv[2] = __float2bfloat16((xv.z - mu) * rstd * gv.z + bv.z);
  hv[3] = __float2bfloat16((xv.w - mu) * rstd * gv.w + bv.w);
  *(uint2*)(h + (size_t)row * DIM + tid * 4) = *(uint2*)hv;
}

// ---------------------------------------------------------------------------
// GEMM: C[M,N] = A[M,K](bf16,row-major) x Bt[N,K](bf16, = B^T).
// 128xBN tile, BK=64, **8 waves (512 thr, 4x2 wave grid)** on the replay-
// proven single-buffer stage->sync->compute->sync loop. Per-wave output
// 32 x BN/2 (acc[2][NW]); staging = 2 A-gld + BN/64 B-gld per thread (512
// lanes cover one 8KB 64-row subtile per instruction). Doubles waves/SIMD
// vs the 256-thr variant at equal blocks/CU — latency hiding via TLP.
// SWZ: bijective XCD swizzle (nwg%8==0).
// EPI 0: QKV split (q pre-scaled by CS; vt stores vectorized 8B over j);
// EPI 1: +bias+residual fp32; EPI 2: bf16 gelu.
// ---------------------------------------------------------------------------
template<int EPI, bool SWZ, int BN>
__global__ __launch_bounds__(512, 4) void gemm_t(
    const bf16* __restrict__ A, const bf16* __restrict__ Bt,
    int N, int K,
    const float* __restrict__ bias,
    float* __restrict__ outf, bf16* __restrict__ outb,
    bf16* __restrict__ outq, bf16* __restrict__ outk, bf16* __restrict__ outvt)
{
  constexpr int NW = BN / 32;   // n-frags per wave
  constexpr int NB = BN / 64;   // B staging gld count
  __shared__ alignas(16) bf16 As[128 * 64];
  __shared__ alignas(16) bf16 Bs[BN * 64];
  const int tid  = threadIdx.x;
  const int lane = tid & 63;
  const int wave = tid >> 6;        // 0..7
  const int wr = wave >> 1;         // 0..3 -> rows wr*32
  const int wc = wave & 1;          // cols wc*(BN/2)

  int bx, by;
  if (SWZ) {
    const int gx   = (int)gridDim.x;
    const int nwg  = gx * (int)gridDim.y;
    const int wg   = blockIdx.x + blockIdx.y * gx;
    const int xcd  = wg & 7;
    const int slot = wg >> 3;
    const int id   = xcd * (nwg >> 3) + slot;   // bijective (nwg%8==0)
    by = id / gx;
    bx = id % gx;
  } else {
    bx = blockIdx.x; by = blockIdx.y;
  }
  const int m0 = by * 128, n0 = bx * BN;
  const int sr = tid >> 3, pc = tid & 7;   // sr 0..63
  const int wbase = (tid & ~63) << 4;
  const int lc = pc ^ (sr & 7);

  f32x4 acc[2][NW];
#pragma unroll
  for (int m = 0; m < 2; ++m)
#pragma unroll
    for (int n = 0; n < NW; ++n) acc[m][n] = (f32x4){0.f, 0.f, 0.f, 0.f};

  for (int k0 = 0; k0 < K; k0 += 64) {
#pragma unroll
    for (int it = 0; it < 2; ++it)
      gld_lds16(A + (size_t)(m0 + it * 64 + sr) * K + k0 + lc * 8,
                (char*)As + it * 8192 + wbase);
#pragma unroll
    for (int it = 0; it < NB; ++it)
      gld_lds16(Bt + (size_t)(n0 + it * 64 + sr) * K + k0 + lc * 8,
                (char*)Bs + it * 8192 + wbase);
    __syncthreads();
#pragma unroll
    for (int kk = 0; kk < 2; ++kk) {
      const int cb = kk * 4 + (lane >> 4);
      bf16x8 af[2], bfr[NW];
#pragma unroll
      for (int m = 0; m < 2; ++m) {
        const int r = wr * 32 + m * 16 + (lane & 15);
        af[m] = *(const bf16x8*)((const char*)As + r * 128 + ((cb ^ (r & 7)) << 4));
      }
#pragma unroll
      for (int n = 0; n < NW; ++n) {
        const int r = wc * (BN / 2) + n * 16 + (lane & 15);
        bfr[n] = *(const bf16x8*)((const char*)Bs + r * 128 + ((cb ^ (r & 7)) << 4));
      }
#pragma unroll
      for (int m = 0; m < 2; ++m)
#pragma unroll
        for (int n = 0; n < NW; ++n)
          acc[m][n] = __builtin_amdgcn_mfma_f32_16x16x32_bf16(af[m], bfr[n], acc[m][n], 0, 0, 0);
    }
    __syncthreads();
  }

#pragma unroll
  for (int m = 0; m < 2; ++m) {
    const int rb = m0 + wr * 32 + m * 16 + ((lane >> 4) << 2);
#pragma unroll
    for (int n = 0; n < NW; ++n) {
      const int col = n0 + wc * (BN / 2) + n * 16 + (lane & 15);
      if (EPI == 0 && col >= 2048) {
        // vt store: 4 consecutive tok at fixed d-col -> one 8B store
        const int batch = rb >> 11, tok = rb & 2047;
        const int c = col - 2048;
        union { bf16x4 v4; short s[4]; } w;
#pragma unroll
        for (int j = 0; j < 4; ++j) {
          const bf16 bb = __float2bfloat16(acc[m][n][j]);
          w.s[j] = *(const short*)&bb;
        }
        *(bf16x4*)(outvt + (((size_t)(batch * HEADS + (c >> 6))) * DIMH + (c & 63)) * SEQ + tok)
            = w.v4;
        continue;
      }
#pragma unroll
      for (int j = 0; j < 4; ++j) {
        const int row = rb + j;
        const float v = acc[m][n][j];
        if (EPI == 0) {
          const int batch = row >> 11, tok = row & 2047;
          if (col < 1024) {
            outq[(((size_t)(batch * HEADS + (col >> 6))) * SEQ + tok) * DIMH + (col & 63)] =
                __float2bfloat16(v * CS);
          } else {
            const int c = col - 1024;
            outk[(((size_t)(batch * HEADS + (c >> 6))) * SEQ + tok) * DIMH + (c & 63)] =
                __float2bfloat16(v);
          }
        } else if (EPI == 1) {
          const size_t off = (size_t)row * N + col;
          outf[off] = v + bias[col] + outf[off];
        } else if (EPI == 2) {
          const float t = v + bias[col];
          const float gg = 0.5f * t * (1.0f + erff(t * 0.70710678118654752f));
          outb[(size_t)row * N + col] = __float2bfloat16(gg);
        }
      }
    }
  }
}

// ---------------------------------------------------------------------------
// Flash attention (round-13 replay-proven structure). 8 waves x 32 q-rows
// (QBLK=256, 512 thr), KVBLK=128 (two 64-kv subtiles), double-buffered with
// counted vmcnt + two-barrier ordering. STATIC-MAX softmax.
// NEW: row-sum via MFMA "ones trick" — l[q] = (1^T P)[q] accumulated by
// mfma(onesA, pa, lsum) on the 19%-busy MFMA pipe, replacing 32 adds +
// 4 shfl per subtile on the 49%-busy VALU pipe. Every row of 1^T P equals
// the column sum, so lsum[m][0] = l for lane-local q.
// ---------------------------------------------------------------------------
__global__ __launch_bounds__(512) void attn_kernel(
    const bf16* __restrict__ q, const bf16* __restrict__ k,
    const bf16* __restrict__ vt, bf16* __restrict__ out)
{
  __shared__ alignas(16) bf16 Ks[2][2][64 * 64];
  __shared__ alignas(16) bf16 Vs[2][2][64 * 64];
  const int tid  = threadIdx.x;
  const int lane = tid & 63;
  const int wave = tid >> 6;        // 0..7
  const int g    = lane >> 4;
  const int lm   = lane & 15;
  const int bh   = blockIdx.y;
  const int qw   = blockIdx.x * 256 + wave * 32;
  const int sr = tid >> 3, pc = tid & 7;

  bf16x8 qf[2][2];
#pragma unroll
  for (int m = 0; m < 2; ++m)
#pragma unroll
    for (int kk = 0; kk < 2; ++kk)
      qf[m][kk] = *(const bf16x8*)(q + ((size_t)bh * SEQ + qw + m * 16 + lm) * DIMH
                                   + kk * 32 + g * 8);

  union { bf16x8 v8; short s[8]; } ones_u;
#pragma unroll
  for (int i = 0; i < 8; ++i) ones_u.s[i] = 0x3F80;   // bf16 1.0
  const bf16x8 onesA = ones_u.v8;

  f32x4 ao[2][4];   // O^T: ao[m][n][r] = O[q=qw+m*16+lm][d = n*16 + g*4 + r]
#pragma unroll
  for (int m = 0; m < 2; ++m)
#pragma unroll
    for (int n = 0; n < 4; ++n) ao[m][n] = (f32x4){0.f, 0.f, 0.f, 0.f};
  f32x4 lsum[2] = {(f32x4){0.f, 0.f, 0.f, 0.f}, (f32x4){0.f, 0.f, 0.f, 0.f}};

  const int lc = pc ^ (sr & 7);
  auto stage = [&](int jt2, int buf) {
#pragma unroll
    for (int sub = 0; sub < 2; ++sub) {
      const int jt = jt2 * 2 + sub;
      gld_lds16(k  + ((size_t)bh * SEQ + jt * 64 + sr) * DIMH + lc * 8,
                (char*)&Ks[buf][sub][0] + tid * 16);
      gld_lds16(vt + ((size_t)bh * DIMH + sr) * SEQ + jt * 64 + lc * 8,
                (char*)&Vs[buf][sub][0] + tid * 16);
    }
  };

  stage(0, 0);

  for (int jt2 = 0; jt2 < SEQ / 128; ++jt2) {
    const int buf = jt2 & 1;
    const bool pref = (jt2 + 1 < SEQ / 128);
    if (pref) {
      stage(jt2 + 1, buf ^ 1);
      asm volatile("s_waitcnt vmcnt(4)" ::: "memory");  // own tile-jt2 loads landed
    } else {
      asm volatile("s_waitcnt vmcnt(0)" ::: "memory");
    }
    __builtin_amdgcn_s_barrier();   // all waves' tile-jt2 landed; next in flight

#pragma unroll
    for (int sub = 0; sub < 2; ++sub) {
      f32x4 sa[2][4];
#pragma unroll
      for (int m = 0; m < 2; ++m)
#pragma unroll
        for (int n = 0; n < 4; ++n)
          sa[m][n] = (f32x4){-SMAX, -SMAX, -SMAX, -SMAX};
      __builtin_amdgcn_s_setprio(1);
#pragma unroll
      for (int kk = 0; kk < 2; ++kk)
#pragma unroll
        for (int n = 0; n < 4; ++n) {
          const int row = n * 16 + lm;
          const bf16x8 af = *(const bf16x8*)((const char*)&Ks[buf][sub][0] + row * 128
                                             + (((kk * 4 + g) ^ (row & 7)) << 4));
#pragma unroll
          for (int m = 0; m < 2; ++m)
            sa[m][n] = __builtin_amdgcn_mfma_f32_16x16x32_bf16(af, qf[m][kk], sa[m][n], 0, 0, 0);
        }
      __builtin_amdgcn_s_setprio(0);

      // p = exp2(sa) (static max), pack to bf16 A-fragments; row-sum deferred
      // to the MFMA ones-trick below.
      bf16x8 pa[2][2];
#pragma unroll
      for (int m = 0; m < 2; ++m) {
#pragma unroll
        for (int n = 0; n < 4; ++n)
#pragma unroll
          for (int r = 0; r < 4; ++r)
            sa[m][n][r] = exp2f(sa[m][n][r]);
#pragma unroll
        for (int h = 0; h < 2; ++h) {
          union { bf16x8 v8; short s[8]; } u;
#pragma unroll
          for (int n2 = 0; n2 < 2; ++n2)
#pragma unroll
            for (int r = 0; r < 4; ++r) {
              const bf16 bb = __float2bfloat16(sa[m][h * 2 + n2][r]);
              u.s[n2 * 4 + r] = *(const short*)&bb;
            }
          pa[m][h] = u.v8;
        }
      }

      __builtin_amdgcn_s_setprio(1);
      // l-sum via MFMA: lsum[m] += ones^T x P (every C row = column sum)
#pragma unroll
      for (int m = 0; m < 2; ++m)
#pragma unroll
        for (int kk = 0; kk < 2; ++kk)
          lsum[m] = __builtin_amdgcn_mfma_f32_16x16x32_bf16(onesA, pa[m][kk], lsum[m], 0, 0, 0);
      // O^T += V^T P
#pragma unroll
      for (int n = 0; n < 4; ++n) {
        const int row = n * 16 + lm;
        const char* vb = (const char*)&Vs[buf][sub][0] + row * 128;
        const int sw = row & 7;
#pragma unroll
        for (int kk = 0; kk < 2; ++kk) {
          const bf16x4 lo = *(const bf16x4*)(vb + (((kk * 4 + (g >> 1)) ^ sw) << 4) + (g & 1) * 8);
          const bf16x4 hi = *(const bf16x4*)(vb + (((kk * 4 + 2 + (g >> 1)) ^ sw) << 4) + (g & 1) * 8);
          const bf16x8 vf = __builtin_shufflevector(lo, hi, 0, 1, 2, 3, 4, 5, 6, 7);
#pragma unroll
          for (int m = 0; m < 2; ++m)
            ao[m][n] = __builtin_amdgcn_mfma_f32_16x16x32_bf16(vf, pa[m][kk], ao[m][n], 0, 0, 0);
        }
      }
      __builtin_amdgcn_s_setprio(0);
    }
    __builtin_amdgcn_s_barrier();   // readers of buf done before next stage
  }

  const int batch = bh >> 4, head = bh & 15;
#pragma unroll
  for (int m = 0; m < 2; ++m) {
    const float linv = 1.0f / lsum[m][0];
    const int row = qw + m * 16 + lm;
    bf16* orow = out + ((size_t)batch * SEQ + row) * INNER + head * DIMH;
#pragma unroll
    for (int n = 0; n < 4; ++n) {
      union { bf16x4 v4; short s[4]; } w;
#pragma unroll
      for (int r = 0; r < 4; ++r) {
        const bf16 bb = __float2bfloat16(ao[m][n][r] * linv);
        w.s[r] = *(const short*)&bb;
      }
      *(bf16x4*)(orow + n * 16 + g * 4) = w.v4;
    }
  }
}

// ---------------------------------------------------------------------------
extern "C" void kernel_launch(void* const* d_in, const int* in_sizes, int n_in,
                              void* d_out, int out_size, void* d_ws, size_t ws_size,
                              hipStream_t stream)
{
  (void)in_sizes; (void)n_in; (void)out_size; (void)ws_size;
  const float* x_in = (const float*)d_in[0];
  const float* Wq   = (const float*)d_in[1];
  const float* Wkv  = (const float*)d_in[2];
  const float* Wo   = (const float*)d_in[3];
  const float* bo   = (const float*)d_in[4];
  const float* ln1g = (const float*)d_in[5];
  const float* ln1b = (const float*)d_in[6];
  const float* ln2g = (const float*)d_in[7];
  const float* ln2b = (const float*)d_in[8];
  const float* W1   = (const float*)d_in[9];
  const float* b1   = (const float*)d_in[10];
  const float* W2   = (const float*)d_in[11];
  const float* b2   = (const float*)d_in[12];
  float* xb = (float*)d_out;

  char* ws = (char*)d_ws;
  size_t off = 0;
  auto take = [&](size_t bytes) {
    char* p = ws + off;
    off += (bytes + 255) & ~(size_t)255;
    return p;
  };
  bf16* Wqkvt = (bf16*)take((size_t)DEPTH * 3072 * 1024 * 2);
  bf16* Wot   = (bf16*)take((size_t)DEPTH * 1024 * 1024 * 2);
  bf16* W1t   = (bf16*)take((size_t)DEPTH * 4096 * 1024 * 2);
  bf16* W2t   = (bf16*)take((size_t)DEPTH * 1024 * 4096 * 2);
  bf16* hb    = (bf16*)take((size_t)NTOK * DIM * 2);
  bf16* qbuf  = (bf16*)take((size_t)NTOK * INNER * 2);
  bf16* kbuf  = (bf16*)take((size_t)NTOK * INNER * 2);
  bf16* vtbuf = (bf16*)take((size_t)NTOK * INNER * 2);
  bf16* aobuf = (bf16*)take((size_t)NTOK * INNER * 2);
  bf16* h1buf = (bf16*)take((size_t)NTOK * DFF * 2);

  hipMemcpyAsync(xb, x_in, (size_t)NTOK * DIM * 4, hipMemcpyDeviceToDevice, stream);

  dim3 b256(256);
  dim3 b512(512);
  transpose_convert<<<dim3(32, 32, DEPTH),  b256, 0, stream>>>(Wq,  Wqkvt, 1024, 1024, 0,    3072);
  transpose_convert<<<dim3(64, 32, DEPTH),  b256, 0, stream>>>(Wkv, Wqkvt, 1024, 2048, 1024, 3072);
  transpose_convert<<<dim3(32, 32, DEPTH),  b256, 0, stream>>>(Wo,  Wot,   1024, 1024, 0,    1024);
  transpose_convert<<<dim3(128, 32, DEPTH), b256, 0, stream>>>(W1,  W1t,   1024, 4096, 0,    4096);
  transpose_convert<<<dim3(32, 128, DEPTH), b256, 0, stream>>>(W2,  W2t,   4096, 1024, 0,    1024);

  for (int l = 0; l < DEPTH; ++l) {
    ln_kernel<<<NTOK, b256, 0, stream>>>(xb, ln1g + l * DIM, ln1b + l * DIM, hb);
    gemm_t<0, true, 128><<<dim3(3072 / 128, NTOK / 128), b512, 0, stream>>>(
        hb, Wqkvt + (size_t)l * 3072 * 1024, 3072, 1024,
        nullptr, nullptr, nullptr, qbuf, kbuf, vtbuf);
    attn_kernel<<<dim3(SEQ / 256, 32), b512, 0, stream>>>(qbuf, kbuf, vtbuf, aobuf);
    gemm_t<1, true, 64><<<dim3(1024 / 64, NTOK / 128), b512, 0, stream>>>(
        aobuf, Wot + (size_t)l * 1024 * 1024, 1024, 1024,
        bo + l * DIM, xb, nullptr, nullptr, nullptr, nullptr);
    ln_kernel<<<NTOK, b256, 0, stream>>>(xb, ln2g + l * DIM, ln2b + l * DIM, hb);
    gemm_t<2, true, 128><<<dim3(4096 / 128, NTOK / 128), b512, 0, stream>>>(
        hb, W1t + (size_t)l * 4096 * 1024, 4096, 1024,
        b1 + l * DFF, nullptr, h1buf, nullptr, nullptr, nullptr);
    gemm_t<1, true, 64><<<dim3(1024 / 64, NTOK / 128), b512, 0, stream>>>(
        h1buf, W2t + (size_t)l * 1024 * 4096, 1024, 4096,
        b2 + l * DIM, xb, nullptr, nullptr, nullptr, nullptr);
  }
}

// Round 15
// 1469.653 us; speedup vs baseline: 1.2981x; 1.0423x over previous
//
#include <hip/hip_runtime.h>
#include <hip/hip_bf16.h>
#include <cstdint>
#include <cstddef>

#define DEPTH 6
#define DIM   1024
#define HEADS 16
#define DIMH  64
#define INNER 1024
#define DFF   4096
#define SEQ   2048
#define NTOK  4096   // 2 * 2048

typedef __attribute__((ext_vector_type(8))) short bf16x8;
typedef __attribute__((ext_vector_type(4))) short bf16x4;
typedef __attribute__((ext_vector_type(4))) float f32x4;
typedef __hip_bfloat16 bf16;

#define CS 0.18033688011112042f  // SCALE * log2(e)
#define SMAX 24.0f               // static softmax max (exp2 domain)

__device__ __forceinline__ void gld_lds16(const void* g, void* l) {
  __builtin_amdgcn_global_load_lds(
      (const __attribute__((address_space(1))) unsigned int*)g,
      (__attribute__((address_space(3))) unsigned int*)l,
      16, 0, 0);
}

// ---------------------------------------------------------------------------
// Weight transpose + fp32->bf16 convert: in [D][K][N] -> out [D][orows][K]
// ---------------------------------------------------------------------------
__global__ __launch_bounds__(256) void transpose_convert(
    const float* __restrict__ in, bf16* __restrict__ out,
    int K, int N, int row0, int orows)
{
  __shared__ float tile[32][33];
  const int d  = blockIdx.z;
  const int n0 = blockIdx.x * 32, k0 = blockIdx.y * 32;
  const int c = threadIdx.x & 31, rb = threadIdx.x >> 5;
  const float* src = in + ((size_t)d * K + k0) * N + n0;
#pragma unroll
  for (int rr = 0; rr < 4; ++rr) {
    int r = rb + rr * 8;
    tile[r][c] = src[(size_t)r * N + c];
  }
  __syncthreads();
  bf16* dst = out + ((size_t)d * orows + row0 + n0) * K + k0;
#pragma unroll
  for (int rr = 0; rr < 4; ++rr) {
    int r = rb + rr * 8;
    dst[(size_t)r * K + c] = __float2bfloat16(tile[c][r]);
  }
}

// ---------------------------------------------------------------------------
// LayerNorm: x fp32 [NTOK][DIM] -> h bf16. One block (256 thr) per row.
// ---------------------------------------------------------------------------
__global__ __launch_bounds__(256) void ln_kernel(
    const float* __restrict__ x, const float* __restrict__ g,
    const float* __restrict__ b, bf16* __restrict__ h)
{
  const int row = blockIdx.x;
  const int tid = threadIdx.x;
  const float4 xv = *(const float4*)(x + (size_t)row * DIM + tid * 4);
  float s  = xv.x + xv.y + xv.z + xv.w;
  float s2 = xv.x * xv.x + xv.y * xv.y + xv.z * xv.z + xv.w * xv.w;
#pragma unroll
  for (int off = 1; off < 64; off <<= 1) {
    s  += __shfl_xor(s, off);
    s2 += __shfl_xor(s2, off);
  }
  __shared__ float red[8];
  const int wave = tid >> 6, lane = tid & 63;
  if (lane == 0) { red[wave * 2] = s; red[wave * 2 + 1] = s2; }
  __syncthreads();
  const float ts  = red[0] + red[2] + red[4] + red[6];
  const float ts2 = red[1] + red[3] + red[5] + red[7];
  const float mu  = ts * (1.0f / DIM);
  const float var = ts2 * (1.0f / DIM) - mu * mu;
  const float rstd = rsqrtf(var + 1e-5f);
  const float4 gv = *(const float4*)(g + tid * 4);
  const float4 bv = *(const float4*)(b + tid * 4);
  bf16 hv[4];
  hv[0] = __float2bfloat16((xv.x - mu) * rstd * gv.x + bv.x);
  hv[1] = __float2bfloat16((xv.y - mu) * rstd * gv.y + bv.y);
  hv[2] = __float2bfloat16((xv.z - mu) * rstd * gv.z + bv.z);
  hv[3] = __float2bfloat16((xv.w - mu) * rstd * gv.w + bv.w);
  *(uint2*)(h + (size_t)row * DIM + tid * 4) = *(uint2*)hv;
}

// ---------------------------------------------------------------------------
// GEMM: C[M,N] = A[M,K](bf16,row-major) x Bt[N,K](bf16, = B^T).
// 128xBN tile, 8 waves (512 thr, 4x2 wave grid), replay-proven single-buffer
// stage->sync->compute->sync loop. BK templated: chunk count CH=BK/8, swizzle
// mask CH-1 (BK=64 instantiation is bit-identical to the round-14 kernel).
// BK=128 halves barrier/iteration count for the 2-blocks/CU GEMMs (proj,
// FFN2); QKV/FFN1 stay BK=64 (keeps their 3-4 blocks/CU TLP; LDS small).
// SWZ: bijective XCD swizzle (nwg%8==0).
// EPI 0: QKV split (q pre-scaled by CS; vt stores vectorized 8B over j);
// EPI 1: +bias+residual fp32; EPI 2: bf16 gelu.
// ---------------------------------------------------------------------------
template<int EPI, bool SWZ, int BN, int BK>
__global__ __launch_bounds__(512, 4) void gemm_t(
    const bf16* __restrict__ A, const bf16* __restrict__ Bt,
    int N, int K,
    const float* __restrict__ bias,
    float* __restrict__ outf, bf16* __restrict__ outb,
    bf16* __restrict__ outq, bf16* __restrict__ outk, bf16* __restrict__ outvt)
{
  constexpr int NW = BN / 32;        // n-frags per wave
  constexpr int CH = BK / 8;         // 16B chunks per row
  constexpr int CM = CH - 1;         // swizzle mask
  constexpr int RB = BK * 2;         // bytes per LDS row
  constexpr int RPG = 512 / CH;      // rows covered per gld instruction
  constexpr int NA = 128 / RPG;      // A staging glds
  constexpr int NB = BN / RPG;       // B staging glds
  __shared__ alignas(16) bf16 As[128 * BK];
  __shared__ alignas(16) bf16 Bs[BN * BK];
  const int tid  = threadIdx.x;
  const int lane = tid & 63;
  const int wave = tid >> 6;        // 0..7
  const int wr = wave >> 1;         // 0..3 -> rows wr*32
  const int wc = wave & 1;          // cols wc*(BN/2)

  int bx, by;
  if (SWZ) {
    const int gx   = (int)gridDim.x;
    const int nwg  = gx * (int)gridDim.y;
    const int wg   = blockIdx.x + blockIdx.y * gx;
    const int xcd  = wg & 7;
    const int slot = wg >> 3;
    const int id   = xcd * (nwg >> 3) + slot;   // bijective (nwg%8==0)
    by = id / gx;
    bx = id % gx;
  } else {
    bx = blockIdx.x; by = blockIdx.y;
  }
  const int m0 = by * 128, n0 = bx * BN;
  const int sr = tid / CH, pc = tid % CH;
  const int lc = pc ^ (sr & CM);

  f32x4 acc[2][NW];
#pragma unroll
  for (int m = 0; m < 2; ++m)
#pragma unroll
    for (int n = 0; n < NW; ++n) acc[m][n] = (f32x4){0.f, 0.f, 0.f, 0.f};

  for (int k0 = 0; k0 < K; k0 += BK) {
#pragma unroll
    for (int it = 0; it < NA; ++it)
      gld_lds16(A + (size_t)(m0 + it * RPG + sr) * K + k0 + lc * 8,
                (char*)As + it * 8192 + tid * 16);
#pragma unroll
    for (int it = 0; it < NB; ++it)
      gld_lds16(Bt + (size_t)(n0 + it * RPG + sr) * K + k0 + lc * 8,
                (char*)Bs + it * 8192 + tid * 16);
    __syncthreads();
#pragma unroll
    for (int kk = 0; kk < BK / 32; ++kk) {
      const int cb = kk * 4 + (lane >> 4);
      bf16x8 af[2], bfr[NW];
#pragma unroll
      for (int m = 0; m < 2; ++m) {
        const int r = wr * 32 + m * 16 + (lane & 15);
        af[m] = *(const bf16x8*)((const char*)As + r * RB + ((cb ^ (r & CM)) << 4));
      }
#pragma unroll
      for (int n = 0; n < NW; ++n) {
        const int r = wc * (BN / 2) + n * 16 + (lane & 15);
        bfr[n] = *(const bf16x8*)((const char*)Bs + r * RB + ((cb ^ (r & CM)) << 4));
      }
#pragma unroll
      for (int m = 0; m < 2; ++m)
#pragma unroll
        for (int n = 0; n < NW; ++n)
          acc[m][n] = __builtin_amdgcn_mfma_f32_16x16x32_bf16(af[m], bfr[n], acc[m][n], 0, 0, 0);
    }
    __syncthreads();
  }

#pragma unroll
  for (int m = 0; m < 2; ++m) {
    const int rb = m0 + wr * 32 + m * 16 + ((lane >> 4) << 2);
#pragma unroll
    for (int n = 0; n < NW; ++n) {
      const int col = n0 + wc * (BN / 2) + n * 16 + (lane & 15);
      if (EPI == 0 && col >= 2048) {
        // vt store: 4 consecutive tok at fixed d-col -> one 8B store
        const int batch = rb >> 11, tok = rb & 2047;
        const int c = col - 2048;
        union { bf16x4 v4; short s[4]; } w;
#pragma unroll
        for (int j = 0; j < 4; ++j) {
          const bf16 bb = __float2bfloat16(acc[m][n][j]);
          w.s[j] = *(const short*)&bb;
        }
        *(bf16x4*)(outvt + (((size_t)(batch * HEADS + (c >> 6))) * DIMH + (c & 63)) * SEQ + tok)
            = w.v4;
        continue;
      }
#pragma unroll
      for (int j = 0; j < 4; ++j) {
        const int row = rb + j;
        const float v = acc[m][n][j];
        if (EPI == 0) {
          const int batch = row >> 11, tok = row & 2047;
          if (col < 1024) {
            outq[(((size_t)(batch * HEADS + (col >> 6))) * SEQ + tok) * DIMH + (col & 63)] =
                __float2bfloat16(v * CS);
          } else {
            const int c = col - 1024;
            outk[(((size_t)(batch * HEADS + (c >> 6))) * SEQ + tok) * DIMH + (c & 63)] =
                __float2bfloat16(v);
          }
        } else if (EPI == 1) {
          const size_t off = (size_t)row * N + col;
          outf[off] = v + bias[col] + outf[off];
        } else if (EPI == 2) {
          const float t = v + bias[col];
          const float gg = 0.5f * t * (1.0f + erff(t * 0.70710678118654752f));
          outb[(size_t)row * N + col] = __float2bfloat16(gg);
        }
      }
    }
  }
}

// ---------------------------------------------------------------------------
// Flash attention (round-14 replay-proven, unchanged). 8 waves x 32 q-rows
// (QBLK=256, 512 thr), KVBLK=128 (two 64-kv subtiles), double-buffered with
// counted vmcnt + two-barrier ordering. STATIC-MAX softmax; l-sum via the
// MFMA ones-trick; O^T = mfma(V^T, P) zero-shuffle epilogue.
// ---------------------------------------------------------------------------
__global__ __launch_bounds__(512) void attn_kernel(
    const bf16* __restrict__ q, const bf16* __restrict__ k,
    const bf16* __restrict__ vt, bf16* __restrict__ out)
{
  __shared__ alignas(16) bf16 Ks[2][2][64 * 64];
  __shared__ alignas(16) bf16 Vs[2][2][64 * 64];
  const int tid  = threadIdx.x;
  const int lane = tid & 63;
  const int wave = tid >> 6;        // 0..7
  const int g    = lane >> 4;
  const int lm   = lane & 15;
  const int bh   = blockIdx.y;
  const int qw   = blockIdx.x * 256 + wave * 32;
  const int sr = tid >> 3, pc = tid & 7;

  bf16x8 qf[2][2];
#pragma unroll
  for (int m = 0; m < 2; ++m)
#pragma unroll
    for (int kk = 0; kk < 2; ++kk)
      qf[m][kk] = *(const bf16x8*)(q + ((size_t)bh * SEQ + qw + m * 16 + lm) * DIMH
                                   + kk * 32 + g * 8);

  union { bf16x8 v8; short s[8]; } ones_u;
#pragma unroll
  for (int i = 0; i < 8; ++i) ones_u.s[i] = 0x3F80;   // bf16 1.0
  const bf16x8 onesA = ones_u.v8;

  f32x4 ao[2][4];   // O^T: ao[m][n][r] = O[q=qw+m*16+lm][d = n*16 + g*4 + r]
#pragma unroll
  for (int m = 0; m < 2; ++m)
#pragma unroll
    for (int n = 0; n < 4; ++n) ao[m][n] = (f32x4){0.f, 0.f, 0.f, 0.f};
  f32x4 lsum[2] = {(f32x4){0.f, 0.f, 0.f, 0.f}, (f32x4){0.f, 0.f, 0.f, 0.f}};

  const int lc = pc ^ (sr & 7);
  auto stage = [&](int jt2, int buf) {
#pragma unroll
    for (int sub = 0; sub < 2; ++sub) {
      const int jt = jt2 * 2 + sub;
      gld_lds16(k  + ((size_t)bh * SEQ + jt * 64 + sr) * DIMH + lc * 8,
                (char*)&Ks[buf][sub][0] + tid * 16);
      gld_lds16(vt + ((size_t)bh * DIMH + sr) * SEQ + jt * 64 + lc * 8,
                (char*)&Vs[buf][sub][0] + tid * 16);
    }
  };

  stage(0, 0);

  for (int jt2 = 0; jt2 < SEQ / 128; ++jt2) {
    const int buf = jt2 & 1;
    const bool pref = (jt2 + 1 < SEQ / 128);
    if (pref) {
      stage(jt2 + 1, buf ^ 1);
      asm volatile("s_waitcnt vmcnt(4)" ::: "memory");  // own tile-jt2 loads landed
    } else {
      asm volatile("s_waitcnt vmcnt(0)" ::: "memory");
    }
    __builtin_amdgcn_s_barrier();   // all waves' tile-jt2 landed; next in flight

#pragma unroll
    for (int sub = 0; sub < 2; ++sub) {
      f32x4 sa[2][4];
#pragma unroll
      for (int m = 0; m < 2; ++m)
#pragma unroll
        for (int n = 0; n < 4; ++n)
          sa[m][n] = (f32x4){-SMAX, -SMAX, -SMAX, -SMAX};
      __builtin_amdgcn_s_setprio(1);
#pragma unroll
      for (int kk = 0; kk < 2; ++kk)
#pragma unroll
        for (int n = 0; n < 4; ++n) {
          const int row = n * 16 + lm;
          const bf16x8 af = *(const bf16x8*)((const char*)&Ks[buf][sub][0] + row * 128
                                             + (((kk * 4 + g) ^ (row & 7)) << 4));
#pragma unroll
          for (int m = 0; m < 2; ++m)
            sa[m][n] = __builtin_amdgcn_mfma_f32_16x16x32_bf16(af, qf[m][kk], sa[m][n], 0, 0, 0);
        }
      __builtin_amdgcn_s_setprio(0);

      // p = exp2(sa) (static max), pack to bf16 A-fragments
      bf16x8 pa[2][2];
#pragma unroll
      for (int m = 0; m < 2; ++m) {
#pragma unroll
        for (int n = 0; n < 4; ++n)
#pragma unroll
          for (int r = 0; r < 4; ++r)
            sa[m][n][r] = exp2f(sa[m][n][r]);
#pragma unroll
        for (int h = 0; h < 2; ++h) {
          union { bf16x8 v8; short s[8]; } u;
#pragma unroll
          for (int n2 = 0; n2 < 2; ++n2)
#pragma unroll
            for (int r = 0; r < 4; ++r) {
              const bf16 bb = __float2bfloat16(sa[m][h * 2 + n2][r]);
              u.s[n2 * 4 + r] = *(const short*)&bb;
            }
          pa[m][h] = u.v8;
        }
      }

      __builtin_amdgcn_s_setprio(1);
      // l-sum via MFMA: lsum[m] += ones^T x P (every C row = column sum)
#pragma unroll
      for (int m = 0; m < 2; ++m)
#pragma unroll
        for (int kk = 0; kk < 2; ++kk)
          lsum[m] = __builtin_amdgcn_mfma_f32_16x16x32_bf16(onesA, pa[m][kk], lsum[m], 0, 0, 0);
      // O^T += V^T P
#pragma unroll
      for (int n = 0; n < 4; ++n) {
        const int row = n * 16 + lm;
        const char* vb = (const char*)&Vs[buf][sub][0] + row * 128;
        const int sw = row & 7;
#pragma unroll
        for (int kk = 0; kk < 2; ++kk) {
          const bf16x4 lo = *(const bf16x4*)(vb + (((kk * 4 + (g >> 1)) ^ sw) << 4) + (g & 1) * 8);
          const bf16x4 hi = *(const bf16x4*)(vb + (((kk * 4 + 2 + (g >> 1)) ^ sw) << 4) + (g & 1) * 8);
          const bf16x8 vf = __builtin_shufflevector(lo, hi, 0, 1, 2, 3, 4, 5, 6, 7);
#pragma unroll
          for (int m = 0; m < 2; ++m)
            ao[m][n] = __builtin_amdgcn_mfma_f32_16x16x32_bf16(vf, pa[m][kk], ao[m][n], 0, 0, 0);
        }
      }
      __builtin_amdgcn_s_setprio(0);
    }
    __builtin_amdgcn_s_barrier();   // readers of buf done before next stage
  }

  const int batch = bh >> 4, head = bh & 15;
#pragma unroll
  for (int m = 0; m < 2; ++m) {
    const float linv = 1.0f / lsum[m][0];
    const int row = qw + m * 16 + lm;
    bf16* orow = out + ((size_t)batch * SEQ + row) * INNER + head * DIMH;
#pragma unroll
    for (int n = 0; n < 4; ++n) {
      union { bf16x4 v4; short s[4]; } w;
#pragma unroll
      for (int r = 0; r < 4; ++r) {
        const bf16 bb = __float2bfloat16(ao[m][n][r] * linv);
        w.s[r] = *(const short*)&bb;
      }
      *(bf16x4*)(orow + n * 16 + g * 4) = w.v4;
    }
  }
}

// ---------------------------------------------------------------------------
extern "C" void kernel_launch(void* const* d_in, const int* in_sizes, int n_in,
                              void* d_out, int out_size, void* d_ws, size_t ws_size,
                              hipStream_t stream)
{
  (void)in_sizes; (void)n_in; (void)out_size; (void)ws_size;
  const float* x_in = (const float*)d_in[0];
  const float* Wq   = (const float*)d_in[1];
  const float* Wkv  = (const float*)d_in[2];
  const float* Wo   = (const float*)d_in[3];
  const float* bo   = (const float*)d_in[4];
  const float* ln1g = (const float*)d_in[5];
  const float* ln1b = (const float*)d_in[6];
  const float* ln2g = (const float*)d_in[7];
  const float* ln2b = (const float*)d_in[8];
  const float* W1   = (const float*)d_in[9];
  const float* b1   = (const float*)d_in[10];
  const float* W2   = (const float*)d_in[11];
  const float* b2   = (const float*)d_in[12];
  float* xb = (float*)d_out;

  char* ws = (char*)d_ws;
  size_t off = 0;
  auto take = [&](size_t bytes) {
    char* p = ws + off;
    off += (bytes + 255) & ~(size_t)255;
    return p;
  };
  bf16* Wqkvt = (bf16*)take((size_t)DEPTH * 3072 * 1024 * 2);
  bf16* Wot   = (bf16*)take((size_t)DEPTH * 1024 * 1024 * 2);
  bf16* W1t   = (bf16*)take((size_t)DEPTH * 4096 * 1024 * 2);
  bf16* W2t   = (bf16*)take((size_t)DEPTH * 1024 * 4096 * 2);
  bf16* hb    = (bf16*)take((size_t)NTOK * DIM * 2);
  bf16* qbuf  = (bf16*)take((size_t)NTOK * INNER * 2);
  bf16* kbuf  = (bf16*)take((size_t)NTOK * INNER * 2);
  bf16* vtbuf = (bf16*)take((size_t)NTOK * INNER * 2);
  bf16* aobuf = (bf16*)take((size_t)NTOK * INNER * 2);
  bf16* h1buf = (bf16*)take((size_t)NTOK * DFF * 2);

  hipMemcpyAsync(xb, x_in, (size_t)NTOK * DIM * 4, hipMemcpyDeviceToDevice, stream);

  dim3 b256(256);
  dim3 b512(512);
  transpose_convert<<<dim3(32, 32, DEPTH),  b256, 0, stream>>>(Wq,  Wqkvt, 1024, 1024, 0,    3072);
  transpose_convert<<<dim3(64, 32, DEPTH),  b256, 0, stream>>>(Wkv, Wqkvt, 1024, 2048, 1024, 3072);
  transpose_convert<<<dim3(32, 32, DEPTH),  b256, 0, stream>>>(Wo,  Wot,   1024, 1024, 0,    1024);
  transpose_convert<<<dim3(128, 32, DEPTH), b256, 0, stream>>>(W1,  W1t,   1024, 4096, 0,    4096);
  transpose_convert<<<dim3(32, 128, DEPTH), b256, 0, stream>>>(W2,  W2t,   4096, 1024, 0,    1024);

  for (int l = 0; l < DEPTH; ++l) {
    ln_kernel<<<NTOK, b256, 0, stream>>>(xb, ln1g + l * DIM, ln1b + l * DIM, hb);
    gemm_t<0, true, 128, 64><<<dim3(3072 / 128, NTOK / 128), b512, 0, stream>>>(
        hb, Wqkvt + (size_t)l * 3072 * 1024, 3072, 1024,
        nullptr, nullptr, nullptr, qbuf, kbuf, vtbuf);
    attn_kernel<<<dim3(SEQ / 256, 32), b512, 0, stream>>>(qbuf, kbuf, vtbuf, aobuf);
    gemm_t<1, true, 64, 128><<<dim3(1024 / 64, NTOK / 128), b512, 0, stream>>>(
        aobuf, Wot + (size_t)l * 1024 * 1024, 1024, 1024,
        bo + l * DIM, xb, nullptr, nullptr, nullptr, nullptr);
    ln_kernel<<<NTOK, b256, 0, stream>>>(xb, ln2g + l * DIM, ln2b + l * DIM, hb);
    gemm_t<2, true, 128, 64><<<dim3(4096 / 128, NTOK / 128), b512, 0, stream>>>(
        hb, W1t + (size_t)l * 4096 * 1024, 4096, 1024,
        b1 + l * DFF, nullptr, h1buf, nullptr, nullptr, nullptr);
    gemm_t<1, true, 64, 128><<<dim3(1024 / 64, NTOK / 128), b512, 0, stream>>>(
        h1buf, W2t + (size_t)l * 1024 * 4096, 1024, 4096,
        b2 + l * DIM, xb, nullptr, nullptr, nullptr, nullptr);
  }
}

// Round 16
// 1444.909 us; speedup vs baseline: 1.3203x; 1.0171x over previous
//
#include <hip/hip_runtime.h>
#include <hip/hip_bf16.h>
#include <cstdint>
#include <cstddef>

#define DEPTH 6
#define DIM   1024
#define HEADS 16
#define DIMH  64
#define INNER 1024
#define DFF   4096
#define SEQ   2048
#define NTOK  4096   // 2 * 2048

typedef __attribute__((ext_vector_type(8))) short bf16x8;
typedef __attribute__((ext_vector_type(4))) short bf16x4;
typedef __attribute__((ext_vector_type(4))) float f32x4;
typedef __hip_bfloat16 bf16;

#define CS 0.18033688011112042f  // SCALE * log2(e)
#define SMAX 24.0f               // static softmax max (exp2 domain)

__device__ __forceinline__ void gld_lds16(const void* g, void* l) {
  __builtin_amdgcn_global_load_lds(
      (const __attribute__((address_space(1))) unsigned int*)g,
      (__attribute__((address_space(3))) unsigned int*)l,
      16, 0, 0);
}

// ---------------------------------------------------------------------------
// Weight transpose + fp32->bf16 convert: in [D][K][N] -> out [D][orows][K]
// ---------------------------------------------------------------------------
__global__ __launch_bounds__(256) void transpose_convert(
    const float* __restrict__ in, bf16* __restrict__ out,
    int K, int N, int row0, int orows)
{
  __shared__ float tile[32][33];
  const int d  = blockIdx.z;
  const int n0 = blockIdx.x * 32, k0 = blockIdx.y * 32;
  const int c = threadIdx.x & 31, rb = threadIdx.x >> 5;
  const float* src = in + ((size_t)d * K + k0) * N + n0;
#pragma unroll
  for (int rr = 0; rr < 4; ++rr) {
    int r = rb + rr * 8;
    tile[r][c] = src[(size_t)r * N + c];
  }
  __syncthreads();
  bf16* dst = out + ((size_t)d * orows + row0 + n0) * K + k0;
#pragma unroll
  for (int rr = 0; rr < 4; ++rr) {
    int r = rb + rr * 8;
    dst[(size_t)r * K + c] = __float2bfloat16(tile[c][r]);
  }
}

// ---------------------------------------------------------------------------
// LayerNorm: x fp32 [NTOK][DIM] -> h bf16. One block (256 thr) per row.
// ---------------------------------------------------------------------------
__global__ __launch_bounds__(256) void ln_kernel(
    const float* __restrict__ x, const float* __restrict__ g,
    const float* __restrict__ b, bf16* __restrict__ h)
{
  const int row = blockIdx.x;
  const int tid = threadIdx.x;
  const float4 xv = *(const float4*)(x + (size_t)row * DIM + tid * 4);
  float s  = xv.x + xv.y + xv.z + xv.w;
  float s2 = xv.x * xv.x + xv.y * xv.y + xv.z * xv.z + xv.w * xv.w;
#pragma unroll
  for (int off = 1; off < 64; off <<= 1) {
    s  += __shfl_xor(s, off);
    s2 += __shfl_xor(s2, off);
  }
  __shared__ float red[8];
  const int wave = tid >> 6, lane = tid & 63;
  if (lane == 0) { red[wave * 2] = s; red[wave * 2 + 1] = s2; }
  __syncthreads();
  const float ts  = red[0] + red[2] + red[4] + red[6];
  const float ts2 = red[1] + red[3] + red[5] + red[7];
  const float mu  = ts * (1.0f / DIM);
  const float var = ts2 * (1.0f / DIM) - mu * mu;
  const float rstd = rsqrtf(var + 1e-5f);
  const float4 gv = *(const float4*)(g + tid * 4);
  const float4 bv = *(const float4*)(b + tid * 4);
  bf16 hv[4];
  hv[0] = __float2bfloat16((xv.x - mu) * rstd * gv.x + bv.x);
  hv[1] = __float2bfloat16((xv.y - mu) * rstd * gv.y + bv.y);
  hv[2] = __float2bfloat16((xv.z - mu) * rstd * gv.z + bv.z);
  hv[3] = __float2bfloat16((xv.w - mu) * rstd * gv.w + bv.w);
  *(uint2*)(h + (size_t)row * DIM + tid * 4) = *(uint2*)hv;
}

// ---------------------------------------------------------------------------
// GEMM (round-15 replay-proven, unchanged): 128xBN tile, 8 waves (512 thr),
// single-buffer loop, BK templated (chunk swizzle mask CH-1), bijective XCD
// swizzle. EPI 0: QKV split; EPI 1: +bias+residual fp32; EPI 2: bf16 gelu.
// ---------------------------------------------------------------------------
template<int EPI, bool SWZ, int BN, int BK>
__global__ __launch_bounds__(512, 4) void gemm_t(
    const bf16* __restrict__ A, const bf16* __restrict__ Bt,
    int N, int K,
    const float* __restrict__ bias,
    float* __restrict__ outf, bf16* __restrict__ outb,
    bf16* __restrict__ outq, bf16* __restrict__ outk, bf16* __restrict__ outvt)
{
  constexpr int NW = BN / 32;
  constexpr int CH = BK / 8;
  constexpr int CM = CH - 1;
  constexpr int RB = BK * 2;
  constexpr int RPG = 512 / CH;
  constexpr int NA = 128 / RPG;
  constexpr int NB = BN / RPG;
  __shared__ alignas(16) bf16 As[128 * BK];
  __shared__ alignas(16) bf16 Bs[BN * BK];
  const int tid  = threadIdx.x;
  const int lane = tid & 63;
  const int wave = tid >> 6;
  const int wr = wave >> 1;
  const int wc = wave & 1;

  int bx, by;
  if (SWZ) {
    const int gx   = (int)gridDim.x;
    const int nwg  = gx * (int)gridDim.y;
    const int wg   = blockIdx.x + blockIdx.y * gx;
    const int xcd  = wg & 7;
    const int slot = wg >> 3;
    const int id   = xcd * (nwg >> 3) + slot;   // bijective (nwg%8==0)
    by = id / gx;
    bx = id % gx;
  } else {
    bx = blockIdx.x; by = blockIdx.y;
  }
  const int m0 = by * 128, n0 = bx * BN;
  const int sr = tid / CH, pc = tid % CH;
  const int lc = pc ^ (sr & CM);

  f32x4 acc[2][NW];
#pragma unroll
  for (int m = 0; m < 2; ++m)
#pragma unroll
    for (int n = 0; n < NW; ++n) acc[m][n] = (f32x4){0.f, 0.f, 0.f, 0.f};

  for (int k0 = 0; k0 < K; k0 += BK) {
#pragma unroll
    for (int it = 0; it < NA; ++it)
      gld_lds16(A + (size_t)(m0 + it * RPG + sr) * K + k0 + lc * 8,
                (char*)As + it * 8192 + tid * 16);
#pragma unroll
    for (int it = 0; it < NB; ++it)
      gld_lds16(Bt + (size_t)(n0 + it * RPG + sr) * K + k0 + lc * 8,
                (char*)Bs + it * 8192 + tid * 16);
    __syncthreads();
#pragma unroll
    for (int kk = 0; kk < BK / 32; ++kk) {
      const int cb = kk * 4 + (lane >> 4);
      bf16x8 af[2], bfr[NW];
#pragma unroll
      for (int m = 0; m < 2; ++m) {
        const int r = wr * 32 + m * 16 + (lane & 15);
        af[m] = *(const bf16x8*)((const char*)As + r * RB + ((cb ^ (r & CM)) << 4));
      }
#pragma unroll
      for (int n = 0; n < NW; ++n) {
        const int r = wc * (BN / 2) + n * 16 + (lane & 15);
        bfr[n] = *(const bf16x8*)((const char*)Bs + r * RB + ((cb ^ (r & CM)) << 4));
      }
#pragma unroll
      for (int m = 0; m < 2; ++m)
#pragma unroll
        for (int n = 0; n < NW; ++n)
          acc[m][n] = __builtin_amdgcn_mfma_f32_16x16x32_bf16(af[m], bfr[n], acc[m][n], 0, 0, 0);
    }
    __syncthreads();
  }

#pragma unroll
  for (int m = 0; m < 2; ++m) {
    const int rb = m0 + wr * 32 + m * 16 + ((lane >> 4) << 2);
#pragma unroll
    for (int n = 0; n < NW; ++n) {
      const int col = n0 + wc * (BN / 2) + n * 16 + (lane & 15);
      if (EPI == 0 && col >= 2048) {
        const int batch = rb >> 11, tok = rb & 2047;
        const int c = col - 2048;
        union { bf16x4 v4; short s[4]; } w;
#pragma unroll
        for (int j = 0; j < 4; ++j) {
          const bf16 bb = __float2bfloat16(acc[m][n][j]);
          w.s[j] = *(const short*)&bb;
        }
        *(bf16x4*)(outvt + (((size_t)(batch * HEADS + (c >> 6))) * DIMH + (c & 63)) * SEQ + tok)
            = w.v4;
        continue;
      }
#pragma unroll
      for (int j = 0; j < 4; ++j) {
        const int row = rb + j;
        const float v = acc[m][n][j];
        if (EPI == 0) {
          const int batch = row >> 11, tok = row & 2047;
          if (col < 1024) {
            outq[(((size_t)(batch * HEADS + (col >> 6))) * SEQ + tok) * DIMH + (col & 63)] =
                __float2bfloat16(v * CS);
          } else {
            const int c = col - 1024;
            outk[(((size_t)(batch * HEADS + (c >> 6))) * SEQ + tok) * DIMH + (c & 63)] =
                __float2bfloat16(v);
          }
        } else if (EPI == 1) {
          const size_t off = (size_t)row * N + col;
          outf[off] = v + bias[col] + outf[off];
        } else if (EPI == 2) {
          const float t = v + bias[col];
          const float gg = 0.5f * t * (1.0f + erff(t * 0.70710678118654752f));
          outb[(size_t)row * N + col] = __float2bfloat16(gg);
        }
      }
    }
  }
}

// ---------------------------------------------------------------------------
// Flash attention. 8 waves x 16 q-rows (QBLK=128, 512 thr) -> grid 512
// blocks = 2 blocks/CU (4 waves/SIMD: cross-wave exp2/MFMA overlap — the
// round-14 TLP mechanism applied to attn). KVBLK=128 (two 64-kv subtiles),
// double-buffered, counted vmcnt + two-barrier ordering (replay-proven
// rounds 13-15; m-loop removed, sync structure unchanged). Bijective XCD
// swizzle: 64 consecutive ids/XCD = 4 whole bh -> K/V 2MB L2-resident.
// STATIC-MAX softmax; l-sum via MFMA ones-trick; O^T = mfma(V^T, P).
// ---------------------------------------------------------------------------
__global__ __launch_bounds__(512) void attn_kernel(
    const bf16* __restrict__ q, const bf16* __restrict__ k,
    const bf16* __restrict__ vt, bf16* __restrict__ out)
{
  __shared__ alignas(16) bf16 Ks[2][2][64 * 64];
  __shared__ alignas(16) bf16 Vs[2][2][64 * 64];
  const int tid  = threadIdx.x;
  const int lane = tid & 63;
  const int wave = tid >> 6;        // 0..7
  const int g    = lane >> 4;
  const int lm   = lane & 15;

  // bijective XCD swizzle over the 2D grid (16 x, 32 bh)
  const int gx   = (int)gridDim.x;                  // 16
  const int nwg  = gx * (int)gridDim.y;             // 512
  const int wg   = blockIdx.x + blockIdx.y * gx;
  const int id   = (wg & 7) * (nwg >> 3) + (wg >> 3);
  const int bh   = id / gx;
  const int qw   = (id % gx) * 128 + wave * 16;

  const int sr = tid >> 3, pc = tid & 7;

  bf16x8 qf[2];
#pragma unroll
  for (int kk = 0; kk < 2; ++kk)
    qf[kk] = *(const bf16x8*)(q + ((size_t)bh * SEQ + qw + lm) * DIMH + kk * 32 + g * 8);

  union { bf16x8 v8; short s[8]; } ones_u;
#pragma unroll
  for (int i = 0; i < 8; ++i) ones_u.s[i] = 0x3F80;   // bf16 1.0
  const bf16x8 onesA = ones_u.v8;

  f32x4 ao[4];   // O^T: ao[n][r] = O[q=qw+lm][d = n*16 + g*4 + r]
#pragma unroll
  for (int n = 0; n < 4; ++n) ao[n] = (f32x4){0.f, 0.f, 0.f, 0.f};
  f32x4 lsum = (f32x4){0.f, 0.f, 0.f, 0.f};

  const int lc = pc ^ (sr & 7);
  auto stage = [&](int jt2, int buf) {
#pragma unroll
    for (int sub = 0; sub < 2; ++sub) {
      const int jt = jt2 * 2 + sub;
      gld_lds16(k  + ((size_t)bh * SEQ + jt * 64 + sr) * DIMH + lc * 8,
                (char*)&Ks[buf][sub][0] + tid * 16);
      gld_lds16(vt + ((size_t)bh * DIMH + sr) * SEQ + jt * 64 + lc * 8,
                (char*)&Vs[buf][sub][0] + tid * 16);
    }
  };

  stage(0, 0);

  for (int jt2 = 0; jt2 < SEQ / 128; ++jt2) {
    const int buf = jt2 & 1;
    const bool pref = (jt2 + 1 < SEQ / 128);
    if (pref) {
      stage(jt2 + 1, buf ^ 1);
      asm volatile("s_waitcnt vmcnt(4)" ::: "memory");  // own tile-jt2 loads landed
    } else {
      asm volatile("s_waitcnt vmcnt(0)" ::: "memory");
    }
    __builtin_amdgcn_s_barrier();   // all waves' tile-jt2 landed; next in flight

#pragma unroll
    for (int sub = 0; sub < 2; ++sub) {
      f32x4 sa[4];
#pragma unroll
      for (int n = 0; n < 4; ++n)
        sa[n] = (f32x4){-SMAX, -SMAX, -SMAX, -SMAX};
      __builtin_amdgcn_s_setprio(1);
#pragma unroll
      for (int kk = 0; kk < 2; ++kk)
#pragma unroll
        for (int n = 0; n < 4; ++n) {
          const int row = n * 16 + lm;
          const bf16x8 af = *(const bf16x8*)((const char*)&Ks[buf][sub][0] + row * 128
                                             + (((kk * 4 + g) ^ (row & 7)) << 4));
          sa[n] = __builtin_amdgcn_mfma_f32_16x16x32_bf16(af, qf[kk], sa[n], 0, 0, 0);
        }
      __builtin_amdgcn_s_setprio(0);

      // p = exp2(sa) (static max), pack to bf16 A-fragments
      bf16x8 pa[2];
#pragma unroll
      for (int n = 0; n < 4; ++n)
#pragma unroll
        for (int r = 0; r < 4; ++r)
          sa[n][r] = exp2f(sa[n][r]);
#pragma unroll
      for (int h = 0; h < 2; ++h) {
        union { bf16x8 v8; short s[8]; } u;
#pragma unroll
        for (int n2 = 0; n2 < 2; ++n2)
#pragma unroll
          for (int r = 0; r < 4; ++r) {
            const bf16 bb = __float2bfloat16(sa[h * 2 + n2][r]);
            u.s[n2 * 4 + r] = *(const short*)&bb;
          }
        pa[h] = u.v8;
      }

      __builtin_amdgcn_s_setprio(1);
      // l-sum via MFMA: lsum += ones^T x P (every C row = column sum)
#pragma unroll
      for (int kk = 0; kk < 2; ++kk)
        lsum = __builtin_amdgcn_mfma_f32_16x16x32_bf16(onesA, pa[kk], lsum, 0, 0, 0);
      // O^T += V^T P
#pragma unroll
      for (int n = 0; n < 4; ++n) {
        const int row = n * 16 + lm;
        const char* vb = (const char*)&Vs[buf][sub][0] + row * 128;
        const int sw = row & 7;
#pragma unroll
        for (int kk = 0; kk < 2; ++kk) {
          const bf16x4 lo = *(const bf16x4*)(vb + (((kk * 4 + (g >> 1)) ^ sw) << 4) + (g & 1) * 8);
          const bf16x4 hi = *(const bf16x4*)(vb + (((kk * 4 + 2 + (g >> 1)) ^ sw) << 4) + (g & 1) * 8);
          const bf16x8 vf = __builtin_shufflevector(lo, hi, 0, 1, 2, 3, 4, 5, 6, 7);
          ao[n] = __builtin_amdgcn_mfma_f32_16x16x32_bf16(vf, pa[kk], ao[n], 0, 0, 0);
        }
      }
      __builtin_amdgcn_s_setprio(0);
    }
    __builtin_amdgcn_s_barrier();   // readers of buf done before next stage
  }

  const int batch = bh >> 4, head = bh & 15;
  const float linv = 1.0f / lsum[0];
  const int row = qw + lm;
  bf16* orow = out + ((size_t)batch * SEQ + row) * INNER + head * DIMH;
#pragma unroll
  for (int n = 0; n < 4; ++n) {
    union { bf16x4 v4; short s[4]; } w;
#pragma unroll
    for (int r = 0; r < 4; ++r) {
      const bf16 bb = __float2bfloat16(ao[n][r] * linv);
      w.s[r] = *(const short*)&bb;
    }
    *(bf16x4*)(orow + n * 16 + g * 4) = w.v4;
  }
}

// ---------------------------------------------------------------------------
extern "C" void kernel_launch(void* const* d_in, const int* in_sizes, int n_in,
                              void* d_out, int out_size, void* d_ws, size_t ws_size,
                              hipStream_t stream)
{
  (void)in_sizes; (void)n_in; (void)out_size; (void)ws_size;
  const float* x_in = (const float*)d_in[0];
  const float* Wq   = (const float*)d_in[1];
  const float* Wkv  = (const float*)d_in[2];
  const float* Wo   = (const float*)d_in[3];
  const float* bo   = (const float*)d_in[4];
  const float* ln1g = (const float*)d_in[5];
  const float* ln1b = (const float*)d_in[6];
  const float* ln2g = (const float*)d_in[7];
  const float* ln2b = (const float*)d_in[8];
  const float* W1   = (const float*)d_in[9];
  const float* b1   = (const float*)d_in[10];
  const float* W2   = (const float*)d_in[11];
  const float* b2   = (const float*)d_in[12];
  float* xb = (float*)d_out;

  char* ws = (char*)d_ws;
  size_t off = 0;
  auto take = [&](size_t bytes) {
    char* p = ws + off;
    off += (bytes + 255) & ~(size_t)255;
    return p;
  };
  bf16* Wqkvt = (bf16*)take((size_t)DEPTH * 3072 * 1024 * 2);
  bf16* Wot   = (bf16*)take((size_t)DEPTH * 1024 * 1024 * 2);
  bf16* W1t   = (bf16*)take((size_t)DEPTH * 4096 * 1024 * 2);
  bf16* W2t   = (bf16*)take((size_t)DEPTH * 1024 * 4096 * 2);
  bf16* hb    = (bf16*)take((size_t)NTOK * DIM * 2);
  bf16* qbuf  = (bf16*)take((size_t)NTOK * INNER * 2);
  bf16* kbuf  = (bf16*)take((size_t)NTOK * INNER * 2);
  bf16* vtbuf = (bf16*)take((size_t)NTOK * INNER * 2);
  bf16* aobuf = (bf16*)take((size_t)NTOK * INNER * 2);
  bf16* h1buf = (bf16*)take((size_t)NTOK * DFF * 2);

  hipMemcpyAsync(xb, x_in, (size_t)NTOK * DIM * 4, hipMemcpyDeviceToDevice, stream);

  dim3 b256(256);
  dim3 b512(512);
  transpose_convert<<<dim3(32, 32, DEPTH),  b256, 0, stream>>>(Wq,  Wqkvt, 1024, 1024, 0,    3072);
  transpose_convert<<<dim3(64, 32, DEPTH),  b256, 0, stream>>>(Wkv, Wqkvt, 1024, 2048, 1024, 3072);
  transpose_convert<<<dim3(32, 32, DEPTH),  b256, 0, stream>>>(Wo,  Wot,   1024, 1024, 0,    1024);
  transpose_convert<<<dim3(128, 32, DEPTH), b256, 0, stream>>>(W1,  W1t,   1024, 4096, 0,    4096);
  transpose_convert<<<dim3(32, 128, DEPTH), b256, 0, stream>>>(W2,  W2t,   4096, 1024, 0,    1024);

  for (int l = 0; l < DEPTH; ++l) {
    ln_kernel<<<NTOK, b256, 0, stream>>>(xb, ln1g + l * DIM, ln1b + l * DIM, hb);
    gemm_t<0, true, 128, 64><<<dim3(3072 / 128, NTOK / 128), b512, 0, stream>>>(
        hb, Wqkvt + (size_t)l * 3072 * 1024, 3072, 1024,
        nullptr, nullptr, nullptr, qbuf, kbuf, vtbuf);
    attn_kernel<<<dim3(SEQ / 128, 32), b512, 0, stream>>>(qbuf, kbuf, vtbuf, aobuf);
    gemm_t<1, true, 64, 128><<<dim3(1024 / 64, NTOK / 128), b512, 0, stream>>>(
        aobuf, Wot + (size_t)l * 1024 * 1024, 1024, 1024,
        bo + l * DIM, xb, nullptr, nullptr, nullptr, nullptr);
    ln_kernel<<<NTOK, b256, 0, stream>>>(xb, ln2g + l * DIM, ln2b + l * DIM, hb);
    gemm_t<2, true, 128, 64><<<dim3(4096 / 128, NTOK / 128), b512, 0, stream>>>(
        hb, W1t + (size_t)l * 4096 * 1024, 4096, 1024,
        b1 + l * DFF, nullptr, h1buf, nullptr, nullptr, nullptr);
    gemm_t<1, true, 64, 128><<<dim3(1024 / 64, NTOK / 128), b512, 0, stream>>>(
        h1buf, W2t + (size_t)l * 1024 * 4096, 1024, 4096,
        b2 + l * DIM, xb, nullptr, nullptr, nullptr, nullptr);
  }
}